// Round 8
// baseline (1016.339 us; speedup 1.0000x reference)
//
#include <hip/hip_runtime.h>

#define DD 128
#define KTOT 384
#define BM 64
#define LDK 392          // 384 + 8 bf16 pad -> row stride 196 dwords (bank-uniform)
#define SCAN_TILE 1024

typedef __attribute__((ext_vector_type(8))) short short8;
typedef __attribute__((ext_vector_type(8))) unsigned short ushort8;
typedef __attribute__((ext_vector_type(4))) float floatx4;

__device__ __forceinline__ unsigned short f2b(float f) {
    union { float f; unsigned u; } v; v.f = f;
    return (unsigned short)((v.u + 0x7fffu + ((v.u >> 16) & 1u)) >> 16);
}
__device__ __forceinline__ float b2f(unsigned short u) {
    union { unsigned u; float f; } v; v.u = ((unsigned)u) << 16;
    return v.f;
}

// ---------------- edge dtype probe: int64 arrays have all-zero odd int32 words ----------
__global__ __launch_bounds__(256) void detect_i32(const int* __restrict__ p, int nodd,
                                                  int* __restrict__ flag)
{
    int i = blockIdx.x * 256 + threadIdx.x;
    if (i < nodd && p[2 * i + 1] != 0) atomicOr(flag, 1);
}

// ---------------- x -> bf16 ----------------
__global__ __launch_bounds__(256) void cvt_bf16(const float* __restrict__ in,
                                                unsigned short* __restrict__ out, int n8)
{
    int i = blockIdx.x * 256 + threadIdx.x;
    if (i >= n8) return;
    float4 v0 = *(const float4*)(in + (size_t)i * 8);
    float4 v1 = *(const float4*)(in + (size_t)i * 8 + 4);
    ushort8 r;
    r[0]=f2b(v0.x); r[1]=f2b(v0.y); r[2]=f2b(v0.z); r[3]=f2b(v0.w);
    r[4]=f2b(v1.x); r[5]=f2b(v1.y); r[6]=f2b(v1.z); r[7]=f2b(v1.w);
    *(ushort8*)(out + (size_t)i * 8) = r;
}

// ---------------- weight prep: WT[l][dst][i][k] bf16 (combined, W^T layout) ----------
__global__ __launch_bounds__(256) void build_wcomb(
    const float* __restrict__ Wl, const float* __restrict__ bl,
    const float* __restrict__ Wr, unsigned short* __restrict__ WT, float* __restrict__ bc)
{
    int idx = blockIdx.x * 256 + threadIdx.x;
    if (idx < 2 * 2 * DD * KTOT) {
        int k  = idx % KTOT;
        int t1 = idx / KTOT;
        int i  = t1 & 127;
        int t2 = t1 >> 7;
        int dt = t2 & 1;      // 0 = dst d, 1 = dst m
        int l  = t2 >> 1;
        int ta = dt ? 1 : 0;  // d: dd(0), m: mm(1)
        int tb = dt ? 2 : 3;  // d: md(3), m: dm(2)
        float v;
        if (k < 128) {
            v = Wl[(((size_t)(l * 4 + ta) * 128 + i) << 7) + k];
        } else if (k < 256) {
            v = Wl[(((size_t)(l * 4 + tb) * 128 + i) << 7) + (k - 128)];
        } else {
            int kk = k - 256;
            v = Wr[(((size_t)(l * 4 + ta) * 128 + i) << 7) + kk]
              + Wr[(((size_t)(l * 4 + tb) * 128 + i) << 7) + kk];
        }
        WT[idx] = f2b(v);
    }
    if (idx < 512) {
        int i  = idx & 127;
        int t2 = idx >> 7;
        int dt = t2 & 1;
        int l  = t2 >> 1;
        int ta = dt ? 1 : 0;
        int tb = dt ? 2 : 3;
        bc[idx] = bl[(l * 4 + ta) * 128 + i] + bl[(l * 4 + tb) * 128 + i];
    }
}

// ---------------- unified degree count over all 4 edge types (raw int32/int64) ---------
__global__ __launch_bounds__(256) void count_all(
    const void* __restrict__ e0, const void* __restrict__ e1,
    const void* __restrict__ e2, const void* __restrict__ e3,
    int E0, int E1, int E2, int E3,
    const int* __restrict__ flag, int* __restrict__ cnt_all, int N)
{
    int e = blockIdx.x * 256 + threadIdx.x;
    const void* ep; int El, type;
    if (e < E0)                 { ep = e0; El = E0; type = 0; }
    else if ((e -= E0) < E1)    { ep = e1; El = E1; type = 1; }
    else if ((e -= E1) < E2)    { ep = e2; El = E2; type = 2; }
    else if ((e -= E2) < E3)    { ep = e3; El = E3; type = 3; }
    else return;
    int d = (*flag) ? ((const int*)ep)[(size_t)El + e]
                    : (int)((const long long*)ep)[(size_t)El + e];
    atomicAdd(&cnt_all[type * N + d], 1);
}

// ---------------- exclusive scan over 4N (3-pass) ----------------
__global__ __launch_bounds__(256) void scan1(const int* __restrict__ in, int n,
                                             int* __restrict__ out, int* __restrict__ bsum)
{
    __shared__ int s[256];
    const int t = threadIdx.x;
    const int base = blockIdx.x * SCAN_TILE + t * 4;
    int c0 = (base + 0) < n ? in[base + 0] : 0;
    int c1 = (base + 1) < n ? in[base + 1] : 0;
    int c2 = (base + 2) < n ? in[base + 2] : 0;
    int c3 = (base + 3) < n ? in[base + 3] : 0;
    int tsum = c0 + c1 + c2 + c3;
    s[t] = tsum;
    __syncthreads();
    for (int d = 1; d < 256; d <<= 1) {
        int v = (t >= d) ? s[t - d] : 0;
        __syncthreads();
        s[t] += v;
        __syncthreads();
    }
    int excl = s[t] - tsum;
    if (base + 0 < n) out[base + 0] = excl;
    if (base + 1 < n) out[base + 1] = excl + c0;
    if (base + 2 < n) out[base + 2] = excl + c0 + c1;
    if (base + 3 < n) out[base + 3] = excl + c0 + c1 + c2;
    if (t == 255) bsum[blockIdx.x] = s[255];
}

__global__ __launch_bounds__(1024) void scan_bsum(int* __restrict__ bsum, int nb)
{
    __shared__ int s[1024];
    const int t = threadIdx.x;
    int v = (t < nb) ? bsum[t] : 0;
    s[t] = v;
    __syncthreads();
    for (int d = 1; d < 1024; d <<= 1) {
        int u = (t >= d) ? s[t - d] : 0;
        __syncthreads();
        s[t] += u;
        __syncthreads();
    }
    if (t < nb) bsum[t] = s[t] - v;   // exclusive
}

// rp += block prefix; cur = rp; inv = 1/max(cnt,1)  (make_inv folded in)
__global__ __launch_bounds__(256) void scan_add(int* __restrict__ rp, int* __restrict__ cur,
                                                int n, const int* __restrict__ bsum,
                                                const int* __restrict__ cnt,
                                                float* __restrict__ inv)
{
    int i = blockIdx.x * 256 + threadIdx.x;
    if (i < n) {
        int v = rp[i] + bsum[i / SCAN_TILE];
        rp[i] = v;
        cur[i] = v;
        inv[i] = 1.0f / (float)max(cnt[i], 1);
    }
}

// ---------------- unified CSR fill (raw edges, unified col array) ----------------
__global__ __launch_bounds__(256) void fill_all(
    const void* __restrict__ e0, const void* __restrict__ e1,
    const void* __restrict__ e2, const void* __restrict__ e3,
    int E0, int E1, int E2, int E3,
    const int* __restrict__ flag, int* __restrict__ cur_all,
    int* __restrict__ col, int N)
{
    int e = blockIdx.x * 256 + threadIdx.x;
    const void* ep; int El, type;
    if (e < E0)                 { ep = e0; El = E0; type = 0; }
    else if ((e -= E0) < E1)    { ep = e1; El = E1; type = 1; }
    else if ((e -= E1) < E2)    { ep = e2; El = E2; type = 2; }
    else if ((e -= E2) < E3)    { ep = e3; El = E3; type = 3; }
    else return;
    int s, d;
    if (*flag) {
        s = ((const int*)ep)[e];
        d = ((const int*)ep)[(size_t)El + e];
    } else {
        s = (int)((const long long*)ep)[e];
        d = (int)((const long long*)ep)[(size_t)El + e];
    }
    int slot = atomicAdd(&cur_all[type * N + d], 1);
    col[slot] = s;
}

// ---------------- fused gather-aggregate + MFMA GEMM ----------------
// A-tile = [mean_{e in T0} xself | mean_{e in T1} xother | xself] (bf16, built in LDS),
// out = A @ WT^T + bc (+relu)
__global__ __launch_bounds__(256) void gemm_agg(
    const unsigned short* __restrict__ xself, const unsigned short* __restrict__ xother,
    const int* __restrict__ rp0, const int* __restrict__ cnt0, const float* __restrict__ inv0,
    const int* __restrict__ rp1, const int* __restrict__ cnt1, const float* __restrict__ inv1,
    const int* __restrict__ col, const unsigned short* __restrict__ WT,
    const float* __restrict__ bias, void* __restrict__ outp,
    int relu, int write_f32, int N)
{
    __shared__ unsigned short As[BM * LDK];      // 50176 B
    const int tid  = threadIdx.x;
    const int row0 = blockIdx.x * BM;

    // seg2: copy xself rows (64 rows x 16 chunks of 16B = 1024 chunks, 4/thread)
    #pragma unroll
    for (int it = 0; it < 4; ++it) {
        int idx = tid + it * 256;
        int row = idx >> 4, c = idx & 15;
        int rg = row0 + row; if (rg >= N) rg = N - 1;
        uint4 v = *(const uint4*)(xself + (size_t)rg * DD + c * 8);
        *(uint4*)(&As[row * LDK + 256 + c * 8]) = v;
    }

    // seg0/seg1: gather-mean, 16 threads/row (full 128 cols), 16 rows/pass x 4
    const int trow = tid >> 4;
    const int q    = tid & 15;
    #pragma unroll
    for (int pass = 0; pass < 4; ++pass) {
        int row = pass * 16 + trow;
        int rg  = row0 + row; if (rg >= N) rg = N - 1;

        float acc[8];
        #pragma unroll
        for (int t = 0; t < 8; ++t) acc[t] = 0.f;
        int s0 = rp0[rg], e0 = s0 + cnt0[rg];
        for (int j = s0; j < e0; ++j) {
            ushort8 v = *(const ushort8*)(xself + (size_t)col[j] * DD + q * 8);
            #pragma unroll
            for (int t = 0; t < 8; ++t) acc[t] += b2f(v[t]);
        }
        float sc = inv0[rg];
        ushort8 r;
        #pragma unroll
        for (int t = 0; t < 8; ++t) r[t] = f2b(acc[t] * sc);
        *(ushort8*)(&As[row * LDK + q * 8]) = r;

        #pragma unroll
        for (int t = 0; t < 8; ++t) acc[t] = 0.f;
        int s1 = rp1[rg], e1 = s1 + cnt1[rg];
        for (int j = s1; j < e1; ++j) {
            ushort8 v = *(const ushort8*)(xother + (size_t)col[j] * DD + q * 8);
            #pragma unroll
            for (int t = 0; t < 8; ++t) acc[t] += b2f(v[t]);
        }
        sc = inv1[rg];
        #pragma unroll
        for (int t = 0; t < 8; ++t) r[t] = f2b(acc[t] * sc);
        *(ushort8*)(&As[row * LDK + 128 + q * 8]) = r;
    }
    __syncthreads();

    const int wave = tid >> 6;
    const int lane = tid & 63;
    const int wr = (wave >> 1) * 32;         // 0 / 32
    const int wc = (wave & 1) * 64;          // 0 / 64
    const int fr = lane & 15;
    const int fk = (lane >> 4) * 8;

    floatx4 acc[2][4] = {};
    const unsigned short* wbase = WT + (size_t)(wc + fr) * KTOT + fk;

    short8 a0c, a1c, a0n, a1n, bC[4], bN[4];
    a0c = *(const short8*)(&As[(wr      + fr) * LDK + fk]);
    a1c = *(const short8*)(&As[(wr + 16 + fr) * LDK + fk]);
    #pragma unroll
    for (int c = 0; c < 4; ++c) bC[c] = *(const short8*)(wbase + (size_t)c * 16 * KTOT);

    #pragma unroll
    for (int ks = 0; ks < 12; ++ks) {
        if (ks < 11) {
            int k1 = (ks + 1) * 32;
            a0n = *(const short8*)(&As[(wr      + fr) * LDK + k1 + fk]);
            a1n = *(const short8*)(&As[(wr + 16 + fr) * LDK + k1 + fk]);
            #pragma unroll
            for (int c = 0; c < 4; ++c) bN[c] = *(const short8*)(wbase + (size_t)c * 16 * KTOT + k1);
        }
        #pragma unroll
        for (int c = 0; c < 4; ++c) {
            acc[0][c] = __builtin_amdgcn_mfma_f32_16x16x32_bf16(a0c, bC[c], acc[0][c], 0, 0, 0);
            acc[1][c] = __builtin_amdgcn_mfma_f32_16x16x32_bf16(a1c, bC[c], acc[1][c], 0, 0, 0);
        }
        a0c = a0n; a1c = a1n;
        #pragma unroll
        for (int c = 0; c < 4; ++c) bC[c] = bN[c];
    }

    // epilogue: col = wc + c*16 + (lane&15), row = wr + m*16 + (lane>>4)*4 + i  [m89 layout]
    float* outf = (float*)outp;
    unsigned short* outb = (unsigned short*)outp;
    const int rb = (lane >> 4) * 4;
    #pragma unroll
    for (int c = 0; c < 4; ++c) {
        int ocol = wc + c * 16 + fr;
        float bb = bias[ocol];
        #pragma unroll
        for (int m = 0; m < 2; ++m) {
            #pragma unroll
            for (int i = 0; i < 4; ++i) {
                int orow = row0 + wr + m * 16 + rb + i;
                if (orow >= N) continue;
                float v = acc[m][c][i] + bb;
                if (relu) v = fmaxf(v, 0.f);
                if (write_f32) outf[(size_t)orow * DD + ocol] = v;
                else           outb[(size_t)orow * DD + ocol] = f2b(v);
            }
        }
    }
}

extern "C" void kernel_launch(void* const* d_in, const int* in_sizes, int n_in,
                              void* d_out, int out_size, void* d_ws, size_t ws_size,
                              hipStream_t stream)
{
    const float* x_d = (const float*)d_in[0];
    const float* x_m = (const float*)d_in[1];
    const float* Wl  = (const float*)d_in[6];
    const float* bl  = (const float*)d_in[7];
    const float* Wr  = (const float*)d_in[8];
    float* out = (float*)d_out;

    const int N    = in_sizes[0] / DD;
    const int E_dd = in_sizes[2] / 2;
    const int E_mm = in_sizes[3] / 2;
    const int E_dm = in_sizes[4] / 2;
    const int E_md = in_sizes[5] / 2;
    const int E_tot = E_dd + E_md + E_mm + E_dm;

    char* ws = (char*)d_ws;
    size_t off = 0;
    auto alloc = [&](size_t bytes) {
        void* p = ws + off;
        off += (bytes + 255) & ~(size_t)255;
        return p;
    };
    unsigned short* xb_d  = (unsigned short*)alloc((size_t)N * DD * 2);
    unsigned short* xb_m  = (unsigned short*)alloc((size_t)N * DD * 2);
    unsigned short* hb_d  = (unsigned short*)alloc((size_t)N * DD * 2);
    unsigned short* hb_m  = (unsigned short*)alloc((size_t)N * DD * 2);
    int*   cnt_all = (int*)  alloc((size_t)4 * N * 4);   // order: dd|md|mm|dm
    float* inv_all = (float*)alloc((size_t)4 * N * 4);
    int*   rp_all  = (int*)  alloc((size_t)4 * N * 4);
    int*   cur_all = (int*)  alloc((size_t)4 * N * 4);
    int*   bsum    = (int*)  alloc((size_t)1024 * 4);
    unsigned short* WT = (unsigned short*)alloc((size_t)2 * 2 * DD * KTOT * 2);
    float* bc      = (float*)alloc((size_t)512 * 4);
    int*   col     = (int*)alloc((size_t)E_tot * 4);     // unified (rp is global)
    int*   flag    = (int*)alloc(256);

    const int* cnt_dd = cnt_all,  *cnt_md = cnt_all + N, *cnt_mm = cnt_all + 2*N, *cnt_dm = cnt_all + 3*N;
    const float* inv_dd = inv_all, *inv_md = inv_all + N, *inv_mm = inv_all + 2*N, *inv_dm = inv_all + 3*N;
    const int* rp_dd  = rp_all,   *rp_md  = rp_all + N,  *rp_mm  = rp_all + 2*N,  *rp_dm  = rp_all + 3*N;

    // ---- edge dtype probe ----
    hipMemsetAsync(flag, 0, 256, stream);
    detect_i32<<<4, 256, 0, stream>>>((const int*)d_in[2], 1024, flag);

    // ---- x -> bf16 ----
    const int n8 = N * DD / 8;
    cvt_bf16<<<(n8 + 255) / 256, 256, 0, stream>>>(x_d, xb_d, n8);
    cvt_bf16<<<(n8 + 255) / 256, 256, 0, stream>>>(x_m, xb_m, n8);

    // ---- degrees (unified; raw edges; order dd|md|mm|dm) ----
    hipMemsetAsync(cnt_all, 0, (size_t)4 * N * 4, stream);
    count_all<<<(E_tot + 255) / 256, 256, 0, stream>>>(
        d_in[2], d_in[5], d_in[3], d_in[4], E_dd, E_md, E_mm, E_dm, flag, cnt_all, N);

    // ---- unified exclusive scan over 4N (+ cur copy + inv) ----
    const int n4 = 4 * N;
    const int nsb = (n4 + SCAN_TILE - 1) / SCAN_TILE;
    scan1<<<nsb, 256, 0, stream>>>(cnt_all, n4, rp_all, bsum);
    scan_bsum<<<1, 1024, 0, stream>>>(bsum, nsb);
    scan_add<<<(n4 + 255) / 256, 256, 0, stream>>>(rp_all, cur_all, n4, bsum, cnt_all, inv_all);

    // ---- unified CSR fill ----
    fill_all<<<(E_tot + 255) / 256, 256, 0, stream>>>(
        d_in[2], d_in[5], d_in[3], d_in[4], E_dd, E_md, E_mm, E_dm, flag, cur_all, col, N);

    build_wcomb<<<(2 * 2 * DD * KTOT + 255) / 256, 256, 0, stream>>>(Wl, bl, Wr, WT, bc);

    const int gemm_grid = (N + BM - 1) / BM;
    const unsigned short* xd_cur = xb_d;
    const unsigned short* xm_cur = xb_m;
    for (int l = 0; l < 2; ++l) {
        int relu = (l == 0);
        int wf32 = (l == 1);
        void* od = (l == 1) ? (void*)out : (void*)hb_d;
        void* om = (l == 1) ? (void*)(out + (size_t)N * DD) : (void*)hb_m;

        // dst d: seg0 = dd (gather xd), seg1 = md (gather xm), seg2 = xd
        gemm_agg<<<gemm_grid, 256, 0, stream>>>(
            xd_cur, xm_cur, rp_dd, cnt_dd, inv_dd, rp_md, cnt_md, inv_md, col,
            WT + (size_t)(l * 2 + 0) * DD * KTOT, bc + (l * 2 + 0) * DD, od, relu, wf32, N);

        // dst m: seg0 = mm (gather xm), seg1 = dm (gather xd), seg2 = xm
        gemm_agg<<<gemm_grid, 256, 0, stream>>>(
            xm_cur, xd_cur, rp_mm, cnt_mm, inv_mm, rp_dm, cnt_dm, inv_dm, col,
            WT + (size_t)(l * 2 + 1) * DD * KTOT, bc + (l * 2 + 1) * DD, om, relu, wf32, N);

        xd_cur = hb_d;
        xm_cur = hb_m;
    }
}

// Round 9
// 749.269 us; speedup vs baseline: 1.3564x; 1.3564x over previous
//
#include <hip/hip_runtime.h>

#define DD 128
#define KTOT 384
#define BM 64
#define LDK 392          // 384 + 8 bf16 pad -> row stride 196 dwords (bank-uniform)
#define SCAN_TILE 1024

typedef __attribute__((ext_vector_type(8))) short short8;
typedef __attribute__((ext_vector_type(8))) unsigned short ushort8;
typedef __attribute__((ext_vector_type(4))) float floatx4;

__device__ __forceinline__ unsigned short f2b(float f) {
    union { float f; unsigned u; } v; v.f = f;
    return (unsigned short)((v.u + 0x7fffu + ((v.u >> 16) & 1u)) >> 16);
}
__device__ __forceinline__ float b2f(unsigned short u) {
    union { unsigned u; float f; } v; v.u = ((unsigned)u) << 16;
    return v.f;
}

// ---------------- edge dtype probe: int64 arrays have all-zero odd int32 words ----------
__global__ __launch_bounds__(256) void detect_i32(const int* __restrict__ p, int nodd,
                                                  int* __restrict__ flag)
{
    int i = blockIdx.x * 256 + threadIdx.x;
    if (i < nodd && p[2 * i + 1] != 0) atomicOr(flag, 1);
}

// ---------------- x -> bf16 ----------------
__global__ __launch_bounds__(256) void cvt_bf16(const float* __restrict__ in,
                                                unsigned short* __restrict__ out, int n8)
{
    int i = blockIdx.x * 256 + threadIdx.x;
    if (i >= n8) return;
    float4 v0 = *(const float4*)(in + (size_t)i * 8);
    float4 v1 = *(const float4*)(in + (size_t)i * 8 + 4);
    ushort8 r;
    r[0]=f2b(v0.x); r[1]=f2b(v0.y); r[2]=f2b(v0.z); r[3]=f2b(v0.w);
    r[4]=f2b(v1.x); r[5]=f2b(v1.y); r[6]=f2b(v1.z); r[7]=f2b(v1.w);
    *(ushort8*)(out + (size_t)i * 8) = r;
}

// ---------------- weight prep: WT[l][dst][i][k] bf16 (combined, W^T layout) ----------
__global__ __launch_bounds__(256) void build_wcomb(
    const float* __restrict__ Wl, const float* __restrict__ bl,
    const float* __restrict__ Wr, unsigned short* __restrict__ WT, float* __restrict__ bc)
{
    int idx = blockIdx.x * 256 + threadIdx.x;
    if (idx < 2 * 2 * DD * KTOT) {
        int k  = idx % KTOT;
        int t1 = idx / KTOT;
        int i  = t1 & 127;
        int t2 = t1 >> 7;
        int dt = t2 & 1;      // 0 = dst d, 1 = dst m
        int l  = t2 >> 1;
        int ta = dt ? 1 : 0;  // d: dd(0), m: mm(1)
        int tb = dt ? 2 : 3;  // d: md(3), m: dm(2)
        float v;
        if (k < 128) {
            v = Wl[(((size_t)(l * 4 + ta) * 128 + i) << 7) + k];
        } else if (k < 256) {
            v = Wl[(((size_t)(l * 4 + tb) * 128 + i) << 7) + (k - 128)];
        } else {
            int kk = k - 256;
            v = Wr[(((size_t)(l * 4 + ta) * 128 + i) << 7) + kk]
              + Wr[(((size_t)(l * 4 + tb) * 128 + i) << 7) + kk];
        }
        WT[idx] = f2b(v);
    }
    if (idx < 512) {
        int i  = idx & 127;
        int t2 = idx >> 7;
        int dt = t2 & 1;
        int l  = t2 >> 1;
        int ta = dt ? 1 : 0;
        int tb = dt ? 2 : 3;
        bc[idx] = bl[(l * 4 + ta) * 128 + i] + bl[(l * 4 + tb) * 128 + i];
    }
}

// ---------------- unified degree count over all 4 edge types (raw int32/int64) ---------
__global__ __launch_bounds__(256) void count_all(
    const void* __restrict__ e0, const void* __restrict__ e1,
    const void* __restrict__ e2, const void* __restrict__ e3,
    int E0, int E1, int E2, int E3,
    const int* __restrict__ flag, int* __restrict__ cnt_all, int N)
{
    int e = blockIdx.x * 256 + threadIdx.x;
    const void* ep; int El, type;
    if (e < E0)                 { ep = e0; El = E0; type = 0; }
    else if ((e -= E0) < E1)    { ep = e1; El = E1; type = 1; }
    else if ((e -= E1) < E2)    { ep = e2; El = E2; type = 2; }
    else if ((e -= E2) < E3)    { ep = e3; El = E3; type = 3; }
    else return;
    int d = (*flag) ? ((const int*)ep)[(size_t)El + e]
                    : (int)((const long long*)ep)[(size_t)El + e];
    atomicAdd(&cnt_all[type * N + d], 1);
}

// ---------------- exclusive scan over 4N (3-pass) ----------------
__global__ __launch_bounds__(256) void scan1(const int* __restrict__ in, int n,
                                             int* __restrict__ out, int* __restrict__ bsum)
{
    __shared__ int s[256];
    const int t = threadIdx.x;
    const int base = blockIdx.x * SCAN_TILE + t * 4;
    int c0 = (base + 0) < n ? in[base + 0] : 0;
    int c1 = (base + 1) < n ? in[base + 1] : 0;
    int c2 = (base + 2) < n ? in[base + 2] : 0;
    int c3 = (base + 3) < n ? in[base + 3] : 0;
    int tsum = c0 + c1 + c2 + c3;
    s[t] = tsum;
    __syncthreads();
    for (int d = 1; d < 256; d <<= 1) {
        int v = (t >= d) ? s[t - d] : 0;
        __syncthreads();
        s[t] += v;
        __syncthreads();
    }
    int excl = s[t] - tsum;
    if (base + 0 < n) out[base + 0] = excl;
    if (base + 1 < n) out[base + 1] = excl + c0;
    if (base + 2 < n) out[base + 2] = excl + c0 + c1;
    if (base + 3 < n) out[base + 3] = excl + c0 + c1 + c2;
    if (t == 255) bsum[blockIdx.x] = s[255];
}

__global__ __launch_bounds__(1024) void scan_bsum(int* __restrict__ bsum, int nb)
{
    __shared__ int s[1024];
    const int t = threadIdx.x;
    int v = (t < nb) ? bsum[t] : 0;
    s[t] = v;
    __syncthreads();
    for (int d = 1; d < 1024; d <<= 1) {
        int u = (t >= d) ? s[t - d] : 0;
        __syncthreads();
        s[t] += u;
        __syncthreads();
    }
    if (t < nb) bsum[t] = s[t] - v;   // exclusive
}

// rp += block prefix; cur = rp; inv = 1/max(cnt,1)  (make_inv folded in)
__global__ __launch_bounds__(256) void scan_add(int* __restrict__ rp, int* __restrict__ cur,
                                                int n, const int* __restrict__ bsum,
                                                const int* __restrict__ cnt,
                                                float* __restrict__ inv)
{
    int i = blockIdx.x * 256 + threadIdx.x;
    if (i < n) {
        int v = rp[i] + bsum[i / SCAN_TILE];
        rp[i] = v;
        cur[i] = v;
        inv[i] = 1.0f / (float)max(cnt[i], 1);
    }
}

// ---------------- unified CSR fill (raw edges, unified col array) ----------------
__global__ __launch_bounds__(256) void fill_all(
    const void* __restrict__ e0, const void* __restrict__ e1,
    const void* __restrict__ e2, const void* __restrict__ e3,
    int E0, int E1, int E2, int E3,
    const int* __restrict__ flag, int* __restrict__ cur_all,
    int* __restrict__ col, int N)
{
    int e = blockIdx.x * 256 + threadIdx.x;
    const void* ep; int El, type;
    if (e < E0)                 { ep = e0; El = E0; type = 0; }
    else if ((e -= E0) < E1)    { ep = e1; El = E1; type = 1; }
    else if ((e -= E1) < E2)    { ep = e2; El = E2; type = 2; }
    else if ((e -= E2) < E3)    { ep = e3; El = E3; type = 3; }
    else return;
    int s, d;
    if (*flag) {
        s = ((const int*)ep)[e];
        d = ((const int*)ep)[(size_t)El + e];
    } else {
        s = (int)((const long long*)ep)[e];
        d = (int)((const long long*)ep)[(size_t)El + e];
    }
    int slot = atomicAdd(&cur_all[type * N + d], 1);
    col[slot] = s;
}

// ---------------- gather-aggregate, 16 lanes/node, ILP-4 unrolled ----------------
__global__ __launch_bounds__(256) void aggregate2(
    const unsigned short* __restrict__ xa, const int* __restrict__ rpa,
    const int* __restrict__ cnta, const float* __restrict__ inva,
    const unsigned short* __restrict__ xb, const int* __restrict__ rpb,
    const int* __restrict__ cntb, const float* __restrict__ invb,
    const int* __restrict__ col,
    unsigned short* __restrict__ agg0, unsigned short* __restrict__ agg1, int N)
{
    long long g = (long long)blockIdx.x * 256 + threadIdx.x;
    int node = (int)(g >> 4);
    int q    = (int)(g & 15);          // lane handles 8 bf16 = 16 B
    if (node >= N) return;

    float acc[8];
    ushort8 r;

    // ---- segment A ----
    #pragma unroll
    for (int t = 0; t < 8; ++t) acc[t] = 0.f;
    {
        int j = rpa[node], e = j + cnta[node];
        for (; j + 4 <= e; j += 4) {
            int c0 = col[j], c1 = col[j+1], c2 = col[j+2], c3 = col[j+3];
            ushort8 v0 = *(const ushort8*)(xa + (size_t)c0 * DD + q * 8);
            ushort8 v1 = *(const ushort8*)(xa + (size_t)c1 * DD + q * 8);
            ushort8 v2 = *(const ushort8*)(xa + (size_t)c2 * DD + q * 8);
            ushort8 v3 = *(const ushort8*)(xa + (size_t)c3 * DD + q * 8);
            #pragma unroll
            for (int t = 0; t < 8; ++t)
                acc[t] += (b2f(v0[t]) + b2f(v1[t])) + (b2f(v2[t]) + b2f(v3[t]));
        }
        for (; j < e; ++j) {
            ushort8 v = *(const ushort8*)(xa + (size_t)col[j] * DD + q * 8);
            #pragma unroll
            for (int t = 0; t < 8; ++t) acc[t] += b2f(v[t]);
        }
    }
    float sc = inva[node];
    #pragma unroll
    for (int t = 0; t < 8; ++t) r[t] = f2b(acc[t] * sc);
    *(ushort8*)(agg0 + (size_t)node * DD + q * 8) = r;

    // ---- segment B ----
    #pragma unroll
    for (int t = 0; t < 8; ++t) acc[t] = 0.f;
    {
        int j = rpb[node], e = j + cntb[node];
        for (; j + 4 <= e; j += 4) {
            int c0 = col[j], c1 = col[j+1], c2 = col[j+2], c3 = col[j+3];
            ushort8 v0 = *(const ushort8*)(xb + (size_t)c0 * DD + q * 8);
            ushort8 v1 = *(const ushort8*)(xb + (size_t)c1 * DD + q * 8);
            ushort8 v2 = *(const ushort8*)(xb + (size_t)c2 * DD + q * 8);
            ushort8 v3 = *(const ushort8*)(xb + (size_t)c3 * DD + q * 8);
            #pragma unroll
            for (int t = 0; t < 8; ++t)
                acc[t] += (b2f(v0[t]) + b2f(v1[t])) + (b2f(v2[t]) + b2f(v3[t]));
        }
        for (; j < e; ++j) {
            ushort8 v = *(const ushort8*)(xb + (size_t)col[j] * DD + q * 8);
            #pragma unroll
            for (int t = 0; t < 8; ++t) acc[t] += b2f(v[t]);
        }
    }
    sc = invb[node];
    #pragma unroll
    for (int t = 0; t < 8; ++t) r[t] = f2b(acc[t] * sc);
    *(ushort8*)(agg1 + (size_t)node * DD + q * 8) = r;
}

// ---------------- MFMA GEMM: out = [agg_a | agg_b | x](bf16) @ WT^T + bc (+relu) --------
__global__ __launch_bounds__(256) void gemm_mfma(
    const unsigned short* __restrict__ agg_a, const unsigned short* __restrict__ agg_b,
    const unsigned short* __restrict__ xs, const unsigned short* __restrict__ WT,
    const float* __restrict__ bias, void* __restrict__ outp,
    int relu, int write_f32, int N)
{
    __shared__ unsigned short As[BM * LDK];      // 50176 B
    const int tid  = threadIdx.x;
    const int row0 = blockIdx.x * BM;

    // stage A tile: 64 rows x 48 chunks(16B) = 3072 chunks, 12/thread, coalesced
    #pragma unroll
    for (int it = 0; it < 12; ++it) {
        int i   = tid + it * 256;
        int row = i / 48;
        int c   = i - row * 48;
        int seg = c >> 4;
        int kk  = c & 15;
        int rg  = row0 + row;
        if (rg >= N) rg = N - 1;
        const unsigned short* src = (seg == 0) ? agg_a : (seg == 1) ? agg_b : xs;
        uint4 v = *(const uint4*)(src + (size_t)rg * DD + kk * 8);
        *(uint4*)(&As[row * LDK + seg * 128 + kk * 8]) = v;
    }
    __syncthreads();

    const int wave = tid >> 6;
    const int lane = tid & 63;
    const int wr = (wave >> 1) * 32;         // 0 / 32
    const int wc = (wave & 1) * 64;          // 0 / 64
    const int fr = lane & 15;
    const int fk = (lane >> 4) * 8;

    floatx4 acc[2][4] = {};
    const unsigned short* wbase = WT + (size_t)(wc + fr) * KTOT + fk;

    short8 a0c, a1c, a0n, a1n, bC[4], bN[4];
    a0c = *(const short8*)(&As[(wr      + fr) * LDK + fk]);
    a1c = *(const short8*)(&As[(wr + 16 + fr) * LDK + fk]);
    #pragma unroll
    for (int c = 0; c < 4; ++c) bC[c] = *(const short8*)(wbase + (size_t)c * 16 * KTOT);

    #pragma unroll
    for (int ks = 0; ks < 12; ++ks) {
        if (ks < 11) {
            int k1 = (ks + 1) * 32;
            a0n = *(const short8*)(&As[(wr      + fr) * LDK + k1 + fk]);
            a1n = *(const short8*)(&As[(wr + 16 + fr) * LDK + k1 + fk]);
            #pragma unroll
            for (int c = 0; c < 4; ++c) bN[c] = *(const short8*)(wbase + (size_t)c * 16 * KTOT + k1);
        }
        #pragma unroll
        for (int c = 0; c < 4; ++c) {
            acc[0][c] = __builtin_amdgcn_mfma_f32_16x16x32_bf16(a0c, bC[c], acc[0][c], 0, 0, 0);
            acc[1][c] = __builtin_amdgcn_mfma_f32_16x16x32_bf16(a1c, bC[c], acc[1][c], 0, 0, 0);
        }
        a0c = a0n; a1c = a1n;
        #pragma unroll
        for (int c = 0; c < 4; ++c) bC[c] = bN[c];
    }

    // epilogue: col = wc + c*16 + (lane&15), row = wr + m*16 + (lane>>4)*4 + i  [m89 layout]
    float* outf = (float*)outp;
    unsigned short* outb = (unsigned short*)outp;
    const int rb = (lane >> 4) * 4;
    #pragma unroll
    for (int c = 0; c < 4; ++c) {
        int ocol = wc + c * 16 + fr;
        float bb = bias[ocol];
        #pragma unroll
        for (int m = 0; m < 2; ++m) {
            #pragma unroll
            for (int i = 0; i < 4; ++i) {
                int orow = row0 + wr + m * 16 + rb + i;
                if (orow >= N) continue;
                float v = acc[m][c][i] + bb;
                if (relu) v = fmaxf(v, 0.f);
                if (write_f32) outf[(size_t)orow * DD + ocol] = v;
                else           outb[(size_t)orow * DD + ocol] = f2b(v);
            }
        }
    }
}

extern "C" void kernel_launch(void* const* d_in, const int* in_sizes, int n_in,
                              void* d_out, int out_size, void* d_ws, size_t ws_size,
                              hipStream_t stream)
{
    const float* x_d = (const float*)d_in[0];
    const float* x_m = (const float*)d_in[1];
    const float* Wl  = (const float*)d_in[6];
    const float* bl  = (const float*)d_in[7];
    const float* Wr  = (const float*)d_in[8];
    float* out = (float*)d_out;

    const int N    = in_sizes[0] / DD;
    const int E_dd = in_sizes[2] / 2;
    const int E_mm = in_sizes[3] / 2;
    const int E_dm = in_sizes[4] / 2;
    const int E_md = in_sizes[5] / 2;
    const int E_tot = E_dd + E_md + E_mm + E_dm;

    char* ws = (char*)d_ws;
    size_t off = 0;
    auto alloc = [&](size_t bytes) {
        void* p = ws + off;
        off += (bytes + 255) & ~(size_t)255;
        return p;
    };
    unsigned short* xb_d  = (unsigned short*)alloc((size_t)N * DD * 2);
    unsigned short* xb_m  = (unsigned short*)alloc((size_t)N * DD * 2);
    unsigned short* hb_d  = (unsigned short*)alloc((size_t)N * DD * 2);
    unsigned short* hb_m  = (unsigned short*)alloc((size_t)N * DD * 2);
    unsigned short* agg0  = (unsigned short*)alloc((size_t)N * DD * 2);
    unsigned short* agg1  = (unsigned short*)alloc((size_t)N * DD * 2);
    int*   cnt_all = (int*)  alloc((size_t)4 * N * 4);   // order: dd|md|mm|dm
    float* inv_all = (float*)alloc((size_t)4 * N * 4);
    int*   rp_all  = (int*)  alloc((size_t)4 * N * 4);
    int*   cur_all = (int*)  alloc((size_t)4 * N * 4);
    int*   bsum    = (int*)  alloc((size_t)1024 * 4);
    unsigned short* WT = (unsigned short*)alloc((size_t)2 * 2 * DD * KTOT * 2);
    float* bc      = (float*)alloc((size_t)512 * 4);
    int*   col     = (int*)alloc((size_t)E_tot * 4);     // unified (rp is global)
    int*   flag    = (int*)alloc(256);

    const int* cnt_dd = cnt_all,  *cnt_md = cnt_all + N, *cnt_mm = cnt_all + 2*N, *cnt_dm = cnt_all + 3*N;
    const float* inv_dd = inv_all, *inv_md = inv_all + N, *inv_mm = inv_all + 2*N, *inv_dm = inv_all + 3*N;
    const int* rp_dd  = rp_all,   *rp_md  = rp_all + N,  *rp_mm  = rp_all + 2*N,  *rp_dm  = rp_all + 3*N;

    // ---- edge dtype probe ----
    hipMemsetAsync(flag, 0, 256, stream);
    detect_i32<<<4, 256, 0, stream>>>((const int*)d_in[2], 1024, flag);

    // ---- x -> bf16 ----
    const int n8 = N * DD / 8;
    cvt_bf16<<<(n8 + 255) / 256, 256, 0, stream>>>(x_d, xb_d, n8);
    cvt_bf16<<<(n8 + 255) / 256, 256, 0, stream>>>(x_m, xb_m, n8);

    // ---- degrees (unified; raw edges; order dd|md|mm|dm) ----
    hipMemsetAsync(cnt_all, 0, (size_t)4 * N * 4, stream);
    count_all<<<(E_tot + 255) / 256, 256, 0, stream>>>(
        d_in[2], d_in[5], d_in[3], d_in[4], E_dd, E_md, E_mm, E_dm, flag, cnt_all, N);

    // ---- unified exclusive scan over 4N (+ cur copy + inv) ----
    const int n4 = 4 * N;
    const int nsb = (n4 + SCAN_TILE - 1) / SCAN_TILE;
    scan1<<<nsb, 256, 0, stream>>>(cnt_all, n4, rp_all, bsum);
    scan_bsum<<<1, 1024, 0, stream>>>(bsum, nsb);
    scan_add<<<(n4 + 255) / 256, 256, 0, stream>>>(rp_all, cur_all, n4, bsum, cnt_all, inv_all);

    // ---- unified CSR fill ----
    fill_all<<<(E_tot + 255) / 256, 256, 0, stream>>>(
        d_in[2], d_in[5], d_in[3], d_in[4], E_dd, E_md, E_mm, E_dm, flag, cur_all, col, N);

    build_wcomb<<<(2 * 2 * DD * KTOT + 255) / 256, 256, 0, stream>>>(Wl, bl, Wr, WT, bc);

    const int agg_grid  = (int)(((size_t)N * 16 + 255) / 256);
    const int gemm_grid = (N + BM - 1) / BM;
    const unsigned short* xd_cur = xb_d;
    const unsigned short* xm_cur = xb_m;
    for (int l = 0; l < 2; ++l) {
        int relu = (l == 0);
        int wf32 = (l == 1);
        void* od = (l == 1) ? (void*)out : (void*)hb_d;
        void* om = (l == 1) ? (void*)(out + (size_t)N * DD) : (void*)hb_m;

        // dst d: seg0 = dd (gather xd), seg1 = md (gather xm), seg2 = xd
        aggregate2<<<agg_grid, 256, 0, stream>>>(
            xd_cur, rp_dd, cnt_dd, inv_dd, xm_cur, rp_md, cnt_md, inv_md, col, agg0, agg1, N);
        gemm_mfma<<<gemm_grid, 256, 0, stream>>>(
            agg0, agg1, xd_cur, WT + (size_t)(l * 2 + 0) * DD * KTOT,
            bc + (l * 2 + 0) * DD, od, relu, wf32, N);

        // dst m: seg0 = mm (gather xm), seg1 = dm (gather xd), seg2 = xm
        aggregate2<<<agg_grid, 256, 0, stream>>>(
            xm_cur, rp_mm, cnt_mm, inv_mm, xd_cur, rp_dm, cnt_dm, inv_dm, col, agg0, agg1, N);
        gemm_mfma<<<gemm_grid, 256, 0, stream>>>(
            agg0, agg1, xm_cur, WT + (size_t)(l * 2 + 1) * DD * KTOT,
            bc + (l * 2 + 1) * DD, om, relu, wf32, N);

        xd_cur = hb_d;
        xm_cur = hb_m;
    }
}

// Round 10
// 641.421 us; speedup vs baseline: 1.5845x; 1.1681x over previous
//
#include <hip/hip_runtime.h>

#define DD 128
#define KTOT 384
#define BM 64
#define LDK 392          // 384 + 8 bf16 pad -> row stride 196 dwords (bank-uniform)
#define SCAN_TILE 1024
#define BS_BITS 10
#define BS 1024          // nodes per bucket
#define NBMAX 512        // max buckets (4N <= 512K)
#define CHUNK 2048       // edges per bin_edges block

typedef __attribute__((ext_vector_type(8))) short short8;
typedef __attribute__((ext_vector_type(8))) unsigned short ushort8;
typedef __attribute__((ext_vector_type(4))) float floatx4;

__device__ __forceinline__ unsigned short f2b(float f) {
    union { float f; unsigned u; } v; v.f = f;
    return (unsigned short)((v.u + 0x7fffu + ((v.u >> 16) & 1u)) >> 16);
}
__device__ __forceinline__ float b2f(unsigned short u) {
    union { unsigned u; float f; } v; v.u = ((unsigned)u) << 16;
    return v.f;
}

// ---------------- edge dtype probe: int64 arrays have all-zero odd int32 words ----------
__global__ __launch_bounds__(256) void detect_i32(const int* __restrict__ p, int nodd,
                                                  int* __restrict__ flag)
{
    int i = blockIdx.x * 256 + threadIdx.x;
    if (i < nodd && p[2 * i + 1] != 0) atomicOr(flag, 1);
}

// ---------------- x -> bf16 ----------------
__global__ __launch_bounds__(256) void cvt_bf16(const float* __restrict__ in,
                                                unsigned short* __restrict__ out, int n8)
{
    int i = blockIdx.x * 256 + threadIdx.x;
    if (i >= n8) return;
    float4 v0 = *(const float4*)(in + (size_t)i * 8);
    float4 v1 = *(const float4*)(in + (size_t)i * 8 + 4);
    ushort8 r;
    r[0]=f2b(v0.x); r[1]=f2b(v0.y); r[2]=f2b(v0.z); r[3]=f2b(v0.w);
    r[4]=f2b(v1.x); r[5]=f2b(v1.y); r[6]=f2b(v1.z); r[7]=f2b(v1.w);
    *(ushort8*)(out + (size_t)i * 8) = r;
}

// ---------------- weight prep: WT[l][dst][i][k] bf16 (combined, W^T layout) ----------
__global__ __launch_bounds__(256) void build_wcomb(
    const float* __restrict__ Wl, const float* __restrict__ bl,
    const float* __restrict__ Wr, unsigned short* __restrict__ WT, float* __restrict__ bc)
{
    int idx = blockIdx.x * 256 + threadIdx.x;
    if (idx < 2 * 2 * DD * KTOT) {
        int k  = idx % KTOT;
        int t1 = idx / KTOT;
        int i  = t1 & 127;
        int t2 = t1 >> 7;
        int dt = t2 & 1;      // 0 = dst d, 1 = dst m
        int l  = t2 >> 1;
        int ta = dt ? 1 : 0;  // d: dd(0), m: mm(1)
        int tb = dt ? 2 : 3;  // d: md(3), m: dm(2)
        float v;
        if (k < 128) {
            v = Wl[(((size_t)(l * 4 + ta) * 128 + i) << 7) + k];
        } else if (k < 256) {
            v = Wl[(((size_t)(l * 4 + tb) * 128 + i) << 7) + (k - 128)];
        } else {
            int kk = k - 256;
            v = Wr[(((size_t)(l * 4 + ta) * 128 + i) << 7) + kk]
              + Wr[(((size_t)(l * 4 + tb) * 128 + i) << 7) + kk];
        }
        WT[idx] = f2b(v);
    }
    if (idx < 512) {
        int i  = idx & 127;
        int t2 = idx >> 7;
        int dt = t2 & 1;
        int l  = t2 >> 1;
        int ta = dt ? 1 : 0;
        int tb = dt ? 2 : 3;
        bc[idx] = bl[(l * 4 + ta) * 128 + i] + bl[(l * 4 + tb) * 128 + i];
    }
}

// ---------------- unified degree count over all 4 edge types (raw int32/int64) ---------
__global__ __launch_bounds__(256) void count_all(
    const void* __restrict__ e0, const void* __restrict__ e1,
    const void* __restrict__ e2, const void* __restrict__ e3,
    int E0, int E1, int E2, int E3,
    const int* __restrict__ flag, int* __restrict__ cnt_all, int N)
{
    int e = blockIdx.x * 256 + threadIdx.x;
    const void* ep; int El, type;
    if (e < E0)                 { ep = e0; El = E0; type = 0; }
    else if ((e -= E0) < E1)    { ep = e1; El = E1; type = 1; }
    else if ((e -= E1) < E2)    { ep = e2; El = E2; type = 2; }
    else if ((e -= E2) < E3)    { ep = e3; El = E3; type = 3; }
    else return;
    int d = (*flag) ? ((const int*)ep)[(size_t)El + e]
                    : (int)((const long long*)ep)[(size_t)El + e];
    atomicAdd(&cnt_all[type * N + d], 1);
}

// ---------------- exclusive scan over 4N (3-pass) ----------------
__global__ __launch_bounds__(256) void scan1(const int* __restrict__ in, int n,
                                             int* __restrict__ out, int* __restrict__ bsum)
{
    __shared__ int s[256];
    const int t = threadIdx.x;
    const int base = blockIdx.x * SCAN_TILE + t * 4;
    int c0 = (base + 0) < n ? in[base + 0] : 0;
    int c1 = (base + 1) < n ? in[base + 1] : 0;
    int c2 = (base + 2) < n ? in[base + 2] : 0;
    int c3 = (base + 3) < n ? in[base + 3] : 0;
    int tsum = c0 + c1 + c2 + c3;
    s[t] = tsum;
    __syncthreads();
    for (int d = 1; d < 256; d <<= 1) {
        int v = (t >= d) ? s[t - d] : 0;
        __syncthreads();
        s[t] += v;
        __syncthreads();
    }
    int excl = s[t] - tsum;
    if (base + 0 < n) out[base + 0] = excl;
    if (base + 1 < n) out[base + 1] = excl + c0;
    if (base + 2 < n) out[base + 2] = excl + c0 + c1;
    if (base + 3 < n) out[base + 3] = excl + c0 + c1 + c2;
    if (t == 255) bsum[blockIdx.x] = s[255];
}

__global__ __launch_bounds__(1024) void scan_bsum(int* __restrict__ bsum, int nb)
{
    __shared__ int s[1024];
    const int t = threadIdx.x;
    int v = (t < nb) ? bsum[t] : 0;
    s[t] = v;
    __syncthreads();
    for (int d = 1; d < 1024; d <<= 1) {
        int u = (t >= d) ? s[t - d] : 0;
        __syncthreads();
        s[t] += u;
        __syncthreads();
    }
    if (t < nb) bsum[t] = s[t] - v;   // exclusive
}

// rp += block prefix; inv = 1/max(cnt,1); seed per-bucket stage cursors
__global__ __launch_bounds__(256) void scan_add(int* __restrict__ rp, int n,
                                                const int* __restrict__ bsum,
                                                const int* __restrict__ cnt,
                                                float* __restrict__ inv,
                                                int* __restrict__ bucket_cur)
{
    int i = blockIdx.x * 256 + threadIdx.x;
    if (i < n) {
        int v = rp[i] + bsum[i / SCAN_TILE];
        rp[i] = v;
        inv[i] = 1.0f / (float)max(cnt[i], 1);
        if ((i & (BS - 1)) == 0) bucket_cur[i >> BS_BITS] = v;
    }
}

// ---------------- phase A: LDS-binned edge staging (counting sort by bucket) ----------
// stage[slot] = (src << 10) | (gnode & 1023), grouped by bucket, region == col layout
__global__ __launch_bounds__(512) void bin_edges(
    const void* __restrict__ e0, const void* __restrict__ e1,
    const void* __restrict__ e2, const void* __restrict__ e3,
    int E0, int E1, int E2, int E3,
    const int* __restrict__ flag, int* __restrict__ bucket_cur,
    unsigned* __restrict__ stage, int N, int nb)
{
    __shared__ unsigned sb_pack[CHUNK];
    __shared__ unsigned short sb_b[CHUNK];
    __shared__ int hist[NBMAX];
    __shared__ int offs[NBMAX];
    __shared__ int base[NBMAX];

    const int tid   = threadIdx.x;
    const int E_tot = E0 + E1 + E2 + E3;
    const int e_bas = blockIdx.x * CHUNK;
    const int e_end = min(e_bas + CHUNK, E_tot);
    const int cnt_e = e_end - e_bas;
    const int isI32 = *flag;

    for (int i = tid; i < nb; i += 512) hist[i] = 0;
    __syncthreads();

    unsigned my_pack[4];
    int my_b[4], my_r[4];
    #pragma unroll
    for (int u = 0; u < 4; ++u) {
        my_b[u] = -1;
        int e = e_bas + tid + u * 512;
        if (e < e_end) {
            const void* ep; int El, type, le = e;
            if (le < E0)              { ep = e0; El = E0; type = 0; }
            else if ((le -= E0) < E1) { ep = e1; El = E1; type = 1; }
            else if ((le -= E1) < E2) { ep = e2; El = E2; type = 2; }
            else                      { le -= E2; ep = e3; El = E3; type = 3; }
            int s, d;
            if (isI32) {
                s = ((const int*)ep)[le];
                d = ((const int*)ep)[(size_t)El + le];
            } else {
                s = (int)((const long long*)ep)[le];
                d = (int)((const long long*)ep)[(size_t)El + le];
            }
            int gnode = type * N + d;
            int b = gnode >> BS_BITS;
            my_b[u]    = b;
            my_pack[u] = ((unsigned)s << BS_BITS) | (unsigned)(gnode & (BS - 1));
            my_r[u]    = atomicAdd(&hist[b], 1);
        }
    }
    __syncthreads();

    // exclusive scan of hist -> offs (512-wide Hillis-Steele)
    offs[tid] = (tid < nb) ? hist[tid] : 0;
    __syncthreads();
    for (int d = 1; d < 512; d <<= 1) {
        int v = (tid >= d) ? offs[tid - d] : 0;
        __syncthreads();
        offs[tid] += v;
        __syncthreads();
    }
    if (tid < nb) {
        offs[tid] -= hist[tid];                              // exclusive
        base[tid] = hist[tid] ? atomicAdd(&bucket_cur[tid], hist[tid]) : 0;
    }
    __syncthreads();

    // scatter into bucket-grouped LDS order
    #pragma unroll
    for (int u = 0; u < 4; ++u) {
        if (my_b[u] >= 0) {
            int pos = offs[my_b[u]] + my_r[u];
            sb_pack[pos] = my_pack[u];
            sb_b[pos]    = (unsigned short)my_b[u];
        }
    }
    __syncthreads();

    // flush: consecutive pos -> mostly consecutive global slots (coalesced chunks)
    for (int pos = tid; pos < cnt_e; pos += 512) {
        int b = sb_b[pos];
        stage[base[b] + (pos - offs[b])] = sb_pack[pos];
    }
}

// ---------------- phase B: per-bucket CSR fill (block owns contiguous col span) --------
__global__ __launch_bounds__(512) void fill_from_stage(
    const unsigned* __restrict__ stage, const int* __restrict__ rp_all,
    int n4, int E_tot, int* __restrict__ col)
{
    __shared__ int cur[BS];
    const int tid   = threadIdx.x;
    const int node0 = blockIdx.x << BS_BITS;
    const int nn    = min(BS, n4 - node0);
    for (int i = tid; i < nn; i += 512) cur[i] = rp_all[node0 + i];
    __syncthreads();
    const int rp0 = rp_all[node0];
    const int rp1 = (node0 + nn < n4) ? rp_all[node0 + nn] : E_tot;
    for (int j = rp0 + tid; j < rp1; j += 512) {
        unsigned p = stage[j];
        int slot = atomicAdd(&cur[p & (BS - 1)], 1);
        col[slot] = (int)(p >> BS_BITS);
    }
}

// ---------------- gather-aggregate, 16 lanes/node, ILP-4 unrolled ----------------
__global__ __launch_bounds__(256) void aggregate2(
    const unsigned short* __restrict__ xa, const int* __restrict__ rpa,
    const int* __restrict__ cnta, const float* __restrict__ inva,
    const unsigned short* __restrict__ xb, const int* __restrict__ rpb,
    const int* __restrict__ cntb, const float* __restrict__ invb,
    const int* __restrict__ col,
    unsigned short* __restrict__ agg0, unsigned short* __restrict__ agg1, int N)
{
    long long g = (long long)blockIdx.x * 256 + threadIdx.x;
    int node = (int)(g >> 4);
    int q    = (int)(g & 15);          // lane handles 8 bf16 = 16 B
    if (node >= N) return;

    float acc[8];
    ushort8 r;

    // ---- segment A ----
    #pragma unroll
    for (int t = 0; t < 8; ++t) acc[t] = 0.f;
    {
        int j = rpa[node], e = j + cnta[node];
        for (; j + 4 <= e; j += 4) {
            int c0 = col[j], c1 = col[j+1], c2 = col[j+2], c3 = col[j+3];
            ushort8 v0 = *(const ushort8*)(xa + (size_t)c0 * DD + q * 8);
            ushort8 v1 = *(const ushort8*)(xa + (size_t)c1 * DD + q * 8);
            ushort8 v2 = *(const ushort8*)(xa + (size_t)c2 * DD + q * 8);
            ushort8 v3 = *(const ushort8*)(xa + (size_t)c3 * DD + q * 8);
            #pragma unroll
            for (int t = 0; t < 8; ++t)
                acc[t] += (b2f(v0[t]) + b2f(v1[t])) + (b2f(v2[t]) + b2f(v3[t]));
        }
        for (; j < e; ++j) {
            ushort8 v = *(const ushort8*)(xa + (size_t)col[j] * DD + q * 8);
            #pragma unroll
            for (int t = 0; t < 8; ++t) acc[t] += b2f(v[t]);
        }
    }
    float sc = inva[node];
    #pragma unroll
    for (int t = 0; t < 8; ++t) r[t] = f2b(acc[t] * sc);
    *(ushort8*)(agg0 + (size_t)node * DD + q * 8) = r;

    // ---- segment B ----
    #pragma unroll
    for (int t = 0; t < 8; ++t) acc[t] = 0.f;
    {
        int j = rpb[node], e = j + cntb[node];
        for (; j + 4 <= e; j += 4) {
            int c0 = col[j], c1 = col[j+1], c2 = col[j+2], c3 = col[j+3];
            ushort8 v0 = *(const ushort8*)(xb + (size_t)c0 * DD + q * 8);
            ushort8 v1 = *(const ushort8*)(xb + (size_t)c1 * DD + q * 8);
            ushort8 v2 = *(const ushort8*)(xb + (size_t)c2 * DD + q * 8);
            ushort8 v3 = *(const ushort8*)(xb + (size_t)c3 * DD + q * 8);
            #pragma unroll
            for (int t = 0; t < 8; ++t)
                acc[t] += (b2f(v0[t]) + b2f(v1[t])) + (b2f(v2[t]) + b2f(v3[t]));
        }
        for (; j < e; ++j) {
            ushort8 v = *(const ushort8*)(xb + (size_t)col[j] * DD + q * 8);
            #pragma unroll
            for (int t = 0; t < 8; ++t) acc[t] += b2f(v[t]);
        }
    }
    sc = invb[node];
    #pragma unroll
    for (int t = 0; t < 8; ++t) r[t] = f2b(acc[t] * sc);
    *(ushort8*)(agg1 + (size_t)node * DD + q * 8) = r;
}

// ---------------- MFMA GEMM: out = [agg_a | agg_b | x](bf16) @ WT^T + bc (+relu) --------
__global__ __launch_bounds__(256) void gemm_mfma(
    const unsigned short* __restrict__ agg_a, const unsigned short* __restrict__ agg_b,
    const unsigned short* __restrict__ xs, const unsigned short* __restrict__ WT,
    const float* __restrict__ bias, void* __restrict__ outp,
    int relu, int write_f32, int N)
{
    __shared__ unsigned short As[BM * LDK];      // 50176 B
    const int tid  = threadIdx.x;
    const int row0 = blockIdx.x * BM;

    // stage A tile: 64 rows x 48 chunks(16B) = 3072 chunks, 12/thread, coalesced
    #pragma unroll
    for (int it = 0; it < 12; ++it) {
        int i   = tid + it * 256;
        int row = i / 48;
        int c   = i - row * 48;
        int seg = c >> 4;
        int kk  = c & 15;
        int rg  = row0 + row;
        if (rg >= N) rg = N - 1;
        const unsigned short* src = (seg == 0) ? agg_a : (seg == 1) ? agg_b : xs;
        uint4 v = *(const uint4*)(src + (size_t)rg * DD + kk * 8);
        *(uint4*)(&As[row * LDK + seg * 128 + kk * 8]) = v;
    }
    __syncthreads();

    const int wave = tid >> 6;
    const int lane = tid & 63;
    const int wr = (wave >> 1) * 32;         // 0 / 32
    const int wc = (wave & 1) * 64;          // 0 / 64
    const int fr = lane & 15;
    const int fk = (lane >> 4) * 8;

    floatx4 acc[2][4] = {};
    const unsigned short* wbase = WT + (size_t)(wc + fr) * KTOT + fk;

    short8 a0c, a1c, a0n, a1n, bC[4], bN[4];
    a0c = *(const short8*)(&As[(wr      + fr) * LDK + fk]);
    a1c = *(const short8*)(&As[(wr + 16 + fr) * LDK + fk]);
    #pragma unroll
    for (int c = 0; c < 4; ++c) bC[c] = *(const short8*)(wbase + (size_t)c * 16 * KTOT);

    #pragma unroll
    for (int ks = 0; ks < 12; ++ks) {
        if (ks < 11) {
            int k1 = (ks + 1) * 32;
            a0n = *(const short8*)(&As[(wr      + fr) * LDK + k1 + fk]);
            a1n = *(const short8*)(&As[(wr + 16 + fr) * LDK + k1 + fk]);
            #pragma unroll
            for (int c = 0; c < 4; ++c) bN[c] = *(const short8*)(wbase + (size_t)c * 16 * KTOT + k1);
        }
        #pragma unroll
        for (int c = 0; c < 4; ++c) {
            acc[0][c] = __builtin_amdgcn_mfma_f32_16x16x32_bf16(a0c, bC[c], acc[0][c], 0, 0, 0);
            acc[1][c] = __builtin_amdgcn_mfma_f32_16x16x32_bf16(a1c, bC[c], acc[1][c], 0, 0, 0);
        }
        a0c = a0n; a1c = a1n;
        #pragma unroll
        for (int c = 0; c < 4; ++c) bC[c] = bN[c];
    }

    // epilogue: col = wc + c*16 + (lane&15), row = wr + m*16 + (lane>>4)*4 + i  [m89 layout]
    float* outf = (float*)outp;
    unsigned short* outb = (unsigned short*)outp;
    const int rb = (lane >> 4) * 4;
    #pragma unroll
    for (int c = 0; c < 4; ++c) {
        int ocol = wc + c * 16 + fr;
        float bb = bias[ocol];
        #pragma unroll
        for (int m = 0; m < 2; ++m) {
            #pragma unroll
            for (int i = 0; i < 4; ++i) {
                int orow = row0 + wr + m * 16 + rb + i;
                if (orow >= N) continue;
                float v = acc[m][c][i] + bb;
                if (relu) v = fmaxf(v, 0.f);
                if (write_f32) outf[(size_t)orow * DD + ocol] = v;
                else           outb[(size_t)orow * DD + ocol] = f2b(v);
            }
        }
    }
}

extern "C" void kernel_launch(void* const* d_in, const int* in_sizes, int n_in,
                              void* d_out, int out_size, void* d_ws, size_t ws_size,
                              hipStream_t stream)
{
    const float* x_d = (const float*)d_in[0];
    const float* x_m = (const float*)d_in[1];
    const float* Wl  = (const float*)d_in[6];
    const float* bl  = (const float*)d_in[7];
    const float* Wr  = (const float*)d_in[8];
    float* out = (float*)d_out;

    const int N    = in_sizes[0] / DD;
    const int E_dd = in_sizes[2] / 2;
    const int E_mm = in_sizes[3] / 2;
    const int E_dm = in_sizes[4] / 2;
    const int E_md = in_sizes[5] / 2;
    const int E_tot = E_dd + E_md + E_mm + E_dm;

    char* ws = (char*)d_ws;
    size_t off = 0;
    auto alloc = [&](size_t bytes) {
        void* p = ws + off;
        off += (bytes + 255) & ~(size_t)255;
        return p;
    };
    unsigned short* xb_d  = (unsigned short*)alloc((size_t)N * DD * 2);
    unsigned short* xb_m  = (unsigned short*)alloc((size_t)N * DD * 2);
    unsigned short* hb_d  = (unsigned short*)alloc((size_t)N * DD * 2);
    unsigned short* hb_m  = (unsigned short*)alloc((size_t)N * DD * 2);
    unsigned short* agg0  = (unsigned short*)alloc((size_t)N * DD * 2);
    unsigned short* agg1  = (unsigned short*)alloc((size_t)N * DD * 2);
    int*   cnt_all = (int*)  alloc((size_t)4 * N * 4);   // order: dd|md|mm|dm
    float* inv_all = (float*)alloc((size_t)4 * N * 4);
    int*   rp_all  = (int*)  alloc((size_t)4 * N * 4);
    int*   bsum    = (int*)  alloc((size_t)1024 * 4);
    int*   bucket_cur = (int*)alloc((size_t)NBMAX * 4);
    unsigned short* WT = (unsigned short*)alloc((size_t)2 * 2 * DD * KTOT * 2);
    float* bc      = (float*)alloc((size_t)512 * 4);
    unsigned* stage = (unsigned*)alloc((size_t)E_tot * 4);
    int*   col     = (int*)alloc((size_t)E_tot * 4);
    int*   flag    = (int*)alloc(256);

    const int* cnt_dd = cnt_all,  *cnt_md = cnt_all + N, *cnt_mm = cnt_all + 2*N, *cnt_dm = cnt_all + 3*N;
    const float* inv_dd = inv_all, *inv_md = inv_all + N, *inv_mm = inv_all + 2*N, *inv_dm = inv_all + 3*N;
    const int* rp_dd  = rp_all,   *rp_md  = rp_all + N,  *rp_mm  = rp_all + 2*N,  *rp_dm  = rp_all + 3*N;

    // ---- edge dtype probe ----
    hipMemsetAsync(flag, 0, 256, stream);
    detect_i32<<<4, 256, 0, stream>>>((const int*)d_in[2], 1024, flag);

    // ---- x -> bf16 ----
    const int n8 = N * DD / 8;
    cvt_bf16<<<(n8 + 255) / 256, 256, 0, stream>>>(x_d, xb_d, n8);
    cvt_bf16<<<(n8 + 255) / 256, 256, 0, stream>>>(x_m, xb_m, n8);

    // ---- degrees (unified; raw edges; order dd|md|mm|dm) ----
    hipMemsetAsync(cnt_all, 0, (size_t)4 * N * 4, stream);
    count_all<<<(E_tot + 255) / 256, 256, 0, stream>>>(
        d_in[2], d_in[5], d_in[3], d_in[4], E_dd, E_md, E_mm, E_dm, flag, cnt_all, N);

    // ---- unified exclusive scan over 4N (+ inv + bucket cursor seed) ----
    const int n4 = 4 * N;
    const int nsb = (n4 + SCAN_TILE - 1) / SCAN_TILE;
    scan1<<<nsb, 256, 0, stream>>>(cnt_all, n4, rp_all, bsum);
    scan_bsum<<<1, 1024, 0, stream>>>(bsum, nsb);
    scan_add<<<(n4 + 255) / 256, 256, 0, stream>>>(rp_all, n4, bsum, cnt_all, inv_all, bucket_cur);

    // ---- CSR build: LDS-binned stage, then per-bucket fill ----
    const int nb = (n4 + BS - 1) >> BS_BITS;
    const int nchunks = (E_tot + CHUNK - 1) / CHUNK;
    bin_edges<<<nchunks, 512, 0, stream>>>(
        d_in[2], d_in[5], d_in[3], d_in[4], E_dd, E_md, E_mm, E_dm,
        flag, bucket_cur, stage, N, nb);
    fill_from_stage<<<nb, 512, 0, stream>>>(stage, rp_all, n4, E_tot, col);

    build_wcomb<<<(2 * 2 * DD * KTOT + 255) / 256, 256, 0, stream>>>(Wl, bl, Wr, WT, bc);

    const int agg_grid  = (int)(((size_t)N * 16 + 255) / 256);
    const int gemm_grid = (N + BM - 1) / BM;
    const unsigned short* xd_cur = xb_d;
    const unsigned short* xm_cur = xb_m;
    for (int l = 0; l < 2; ++l) {
        int relu = (l == 0);
        int wf32 = (l == 1);
        void* od = (l == 1) ? (void*)out : (void*)hb_d;
        void* om = (l == 1) ? (void*)(out + (size_t)N * DD) : (void*)hb_m;

        // dst d: seg0 = dd (gather xd), seg1 = md (gather xm), seg2 = xd
        aggregate2<<<agg_grid, 256, 0, stream>>>(
            xd_cur, rp_dd, cnt_dd, inv_dd, xm_cur, rp_md, cnt_md, inv_md, col, agg0, agg1, N);
        gemm_mfma<<<gemm_grid, 256, 0, stream>>>(
            agg0, agg1, xd_cur, WT + (size_t)(l * 2 + 0) * DD * KTOT,
            bc + (l * 2 + 0) * DD, od, relu, wf32, N);

        // dst m: seg0 = mm (gather xm), seg1 = dm (gather xd), seg2 = xm
        aggregate2<<<agg_grid, 256, 0, stream>>>(
            xm_cur, rp_mm, cnt_mm, inv_mm, xd_cur, rp_dm, cnt_dm, inv_dm, col, agg0, agg1, N);
        gemm_mfma<<<gemm_grid, 256, 0, stream>>>(
            agg0, agg1, xm_cur, WT + (size_t)(l * 2 + 1) * DD * KTOT,
            bc + (l * 2 + 1) * DD, om, relu, wf32, N);

        xd_cur = hb_d;
        xm_cur = hb_m;
    }
}

// Round 11
// 549.039 us; speedup vs baseline: 1.8511x; 1.1683x over previous
//
#include <hip/hip_runtime.h>

#define DD 128
#define KTOT 384
#define BM 64
#define LDK 392          // 384 + 8 bf16 pad -> row stride 196 dwords (bank-uniform)
#define BS_BITS 10
#define BS 1024          // nodes per bucket
#define NBMAX 512        // max buckets (4N <= 512K)
#define CHUNK 2048       // edges per bin_edges block
#define CAP 12288        // stage slots per bucket (max expected ~10.6K)

typedef __attribute__((ext_vector_type(8))) short short8;
typedef __attribute__((ext_vector_type(8))) unsigned short ushort8;
typedef __attribute__((ext_vector_type(4))) float floatx4;

__device__ __forceinline__ unsigned short f2b(float f) {
    union { float f; unsigned u; } v; v.f = f;
    return (unsigned short)((v.u + 0x7fffu + ((v.u >> 16) & 1u)) >> 16);
}
__device__ __forceinline__ float b2f(unsigned short u) {
    union { unsigned u; float f; } v; v.u = ((unsigned)u) << 16;
    return v.f;
}

// ---------------- edge dtype probe: int64 arrays have all-zero odd int32 words ----------
__global__ __launch_bounds__(256) void detect_i32(const int* __restrict__ p, int nodd,
                                                  int* __restrict__ flag)
{
    int i = blockIdx.x * 256 + threadIdx.x;
    if (i < nodd && p[2 * i + 1] != 0) atomicOr(flag, 1);
}

// ---------------- x -> bf16 ----------------
__global__ __launch_bounds__(256) void cvt_bf16(const float* __restrict__ in,
                                                unsigned short* __restrict__ out, int n8)
{
    int i = blockIdx.x * 256 + threadIdx.x;
    if (i >= n8) return;
    float4 v0 = *(const float4*)(in + (size_t)i * 8);
    float4 v1 = *(const float4*)(in + (size_t)i * 8 + 4);
    ushort8 r;
    r[0]=f2b(v0.x); r[1]=f2b(v0.y); r[2]=f2b(v0.z); r[3]=f2b(v0.w);
    r[4]=f2b(v1.x); r[5]=f2b(v1.y); r[6]=f2b(v1.z); r[7]=f2b(v1.w);
    *(ushort8*)(out + (size_t)i * 8) = r;
}

// ---------------- weight prep: WT[l][dst][i][k] bf16 (combined, W^T layout) ----------
__global__ __launch_bounds__(256) void build_wcomb(
    const float* __restrict__ Wl, const float* __restrict__ bl,
    const float* __restrict__ Wr, unsigned short* __restrict__ WT, float* __restrict__ bc)
{
    int idx = blockIdx.x * 256 + threadIdx.x;
    if (idx < 2 * 2 * DD * KTOT) {
        int k  = idx % KTOT;
        int t1 = idx / KTOT;
        int i  = t1 & 127;
        int t2 = t1 >> 7;
        int dt = t2 & 1;      // 0 = dst d, 1 = dst m
        int l  = t2 >> 1;
        int ta = dt ? 1 : 0;  // d: dd(0), m: mm(1)
        int tb = dt ? 2 : 3;  // d: md(3), m: dm(2)
        float v;
        if (k < 128) {
            v = Wl[(((size_t)(l * 4 + ta) * 128 + i) << 7) + k];
        } else if (k < 256) {
            v = Wl[(((size_t)(l * 4 + tb) * 128 + i) << 7) + (k - 128)];
        } else {
            int kk = k - 256;
            v = Wr[(((size_t)(l * 4 + ta) * 128 + i) << 7) + kk]
              + Wr[(((size_t)(l * 4 + tb) * 128 + i) << 7) + kk];
        }
        WT[idx] = f2b(v);
    }
    if (idx < 512) {
        int i  = idx & 127;
        int t2 = idx >> 7;
        int dt = t2 & 1;
        int l  = t2 >> 1;
        int ta = dt ? 1 : 0;
        int tb = dt ? 2 : 3;
        bc[idx] = bl[(l * 4 + ta) * 128 + i] + bl[(l * 4 + tb) * 128 + i];
    }
}

// ---------------- phase A: LDS-binned edge staging, fixed-CAP bucket regions ----------
// stage[b*CAP + i] = (src << 10) | (gnode & 1023); bucket_fill[b] accumulates true totals
__global__ __launch_bounds__(512) void bin_edges(
    const void* __restrict__ e0, const void* __restrict__ e1,
    const void* __restrict__ e2, const void* __restrict__ e3,
    int E0, int E1, int E2, int E3,
    const int* __restrict__ flag, int* __restrict__ bucket_fill,
    unsigned* __restrict__ stage,
    unsigned long long* __restrict__ ovf, int* __restrict__ ovf_cnt,
    int N, int nb)
{
    __shared__ unsigned sb_pack[CHUNK];
    __shared__ unsigned short sb_b[CHUNK];
    __shared__ int hist[NBMAX];
    __shared__ int offs[NBMAX];
    __shared__ int base[NBMAX];

    const int tid   = threadIdx.x;
    const int E_tot = E0 + E1 + E2 + E3;
    const int e_bas = blockIdx.x * CHUNK;
    const int e_end = min(e_bas + CHUNK, E_tot);
    const int cnt_e = e_end - e_bas;
    const int isI32 = *flag;

    for (int i = tid; i < nb; i += 512) hist[i] = 0;
    __syncthreads();

    unsigned my_pack[4];
    int my_b[4], my_r[4];
    #pragma unroll
    for (int u = 0; u < 4; ++u) {
        my_b[u] = -1;
        int e = e_bas + tid + u * 512;
        if (e < e_end) {
            const void* ep; int El, type, le = e;
            if (le < E0)              { ep = e0; El = E0; type = 0; }
            else if ((le -= E0) < E1) { ep = e1; El = E1; type = 1; }
            else if ((le -= E1) < E2) { ep = e2; El = E2; type = 2; }
            else                      { le -= E2; ep = e3; El = E3; type = 3; }
            int s, d;
            if (isI32) {
                s = ((const int*)ep)[le];
                d = ((const int*)ep)[(size_t)El + le];
            } else {
                s = (int)((const long long*)ep)[le];
                d = (int)((const long long*)ep)[(size_t)El + le];
            }
            int gnode = type * N + d;
            int b = gnode >> BS_BITS;
            my_b[u]    = b;
            my_pack[u] = ((unsigned)s << BS_BITS) | (unsigned)(gnode & (BS - 1));
            my_r[u]    = atomicAdd(&hist[b], 1);
        }
    }
    __syncthreads();

    // exclusive scan of hist -> offs (512-wide Hillis-Steele)
    offs[tid] = (tid < nb) ? hist[tid] : 0;
    __syncthreads();
    for (int d = 1; d < 512; d <<= 1) {
        int v = (tid >= d) ? offs[tid - d] : 0;
        __syncthreads();
        offs[tid] += v;
        __syncthreads();
    }
    if (tid < nb) {
        offs[tid] -= hist[tid];                              // exclusive
        base[tid] = hist[tid] ? atomicAdd(&bucket_fill[tid], hist[tid]) : 0;
    }
    __syncthreads();

    // scatter into bucket-grouped LDS order
    #pragma unroll
    for (int u = 0; u < 4; ++u) {
        if (my_b[u] >= 0) {
            int pos = offs[my_b[u]] + my_r[u];
            sb_pack[pos] = my_pack[u];
            sb_b[pos]    = (unsigned short)my_b[u];
        }
    }
    __syncthreads();

    // flush: consecutive pos -> consecutive slots within each bucket's CAP region
    for (int pos = tid; pos < cnt_e; pos += 512) {
        int b = sb_b[pos];
        unsigned p = sb_pack[pos];
        int idx = base[b] + (pos - offs[b]);
        if (idx < CAP) {
            stage[(size_t)b * CAP + idx] = p;
        } else {                                             // overflow (expected: never)
            int k = atomicAdd(ovf_cnt, 1);
            int gnode = (b << BS_BITS) | (int)(p & (BS - 1));
            ovf[k] = ((unsigned long long)(unsigned)gnode << 32) | (p >> BS_BITS);
        }
    }
}

// ---------------- exclusive scan over bucket totals (1 block) ----------------
__global__ __launch_bounds__(512) void scan_buckets(const int* __restrict__ fill, int nb,
                                                    int* __restrict__ base)
{
    __shared__ int s[512];
    const int tid = threadIdx.x;
    int v = (tid < nb) ? fill[tid] : 0;
    s[tid] = v;
    __syncthreads();
    for (int d = 1; d < 512; d <<= 1) {
        int u = (tid >= d) ? s[tid - d] : 0;
        __syncthreads();
        s[tid] += u;
        __syncthreads();
    }
    if (tid < nb) base[tid] = s[tid] - v;    // exclusive
}

// ---------------- phase B: per-bucket count + scan + rp/inv + CSR fill ----------------
__global__ __launch_bounds__(512) void fill_from_stage(
    const unsigned* __restrict__ stage, const int* __restrict__ bucket_fill,
    const int* __restrict__ bucket_base,
    const unsigned long long* __restrict__ ovf, const int* __restrict__ ovf_cnt,
    int* __restrict__ rp_all, float* __restrict__ inv_all, int* __restrict__ col, int n4)
{
    __shared__ int cl[BS];     // counts, later cursors
    __shared__ int rl[BS];     // exclusive scan
    __shared__ int w[512];

    const int tid   = threadIdx.x;
    const int b     = blockIdx.x;
    const int node0 = b << BS_BITS;
    const int nn    = min(BS, n4 - node0);

    cl[tid] = 0; cl[tid + 512] = 0;
    __syncthreads();

    const int total  = bucket_fill[b];
    const int nstage = min(total, CAP);
    const unsigned* st = stage + (size_t)b * CAP;
    const int novf = *ovf_cnt;

    for (int j = tid; j < nstage; j += 512)
        atomicAdd(&cl[st[j] & (BS - 1)], 1);
    for (int k = tid; k < novf; k += 512) {
        int g = (int)(ovf[k] >> 32);
        if (g >= node0 && g < node0 + nn) atomicAdd(&cl[g - node0], 1);
    }
    __syncthreads();

    // exclusive scan of cl[0..1023] -> rl
    int a0 = cl[2 * tid], a1 = cl[2 * tid + 1];
    w[tid] = a0 + a1;
    __syncthreads();
    for (int d = 1; d < 512; d <<= 1) {
        int v = (tid >= d) ? w[tid - d] : 0;
        __syncthreads();
        w[tid] += v;
        __syncthreads();
    }
    int excl = w[tid] - a0 - a1;
    rl[2 * tid]     = excl;
    rl[2 * tid + 1] = excl + a0;
    __syncthreads();

    // rp / inv (coalesced)
    const int gbase = bucket_base[b];
    for (int i = tid; i < nn; i += 512) {
        rp_all[node0 + i] = gbase + rl[i];
        inv_all[node0 + i] = 1.0f / (float)max(cl[i], 1);
    }
    if (b == gridDim.x - 1 && tid == 0) rp_all[n4] = gbase + total;
    __syncthreads();

    // cursors = global slot
    for (int i = tid; i < BS; i += 512) cl[i] = gbase + rl[i];
    __syncthreads();

    for (int j = tid; j < nstage; j += 512) {
        unsigned p = st[j];
        int slot = atomicAdd(&cl[p & (BS - 1)], 1);
        col[slot] = (int)(p >> BS_BITS);
    }
    for (int k = tid; k < novf; k += 512) {
        unsigned long long p = ovf[k];
        int g = (int)(p >> 32);
        if (g >= node0 && g < node0 + nn) {
            int slot = atomicAdd(&cl[g - node0], 1);
            col[slot] = (int)(p & 0xffffffffu);
        }
    }
}

// ---------------- gather-aggregate, 16 lanes/node, ILP-4; cnt = rp[n+1]-rp[n] ----------
__global__ __launch_bounds__(256) void aggregate2(
    const unsigned short* __restrict__ xa, const int* __restrict__ rpa,
    const float* __restrict__ inva,
    const unsigned short* __restrict__ xb, const int* __restrict__ rpb,
    const float* __restrict__ invb,
    const int* __restrict__ col,
    unsigned short* __restrict__ agg0, unsigned short* __restrict__ agg1, int N)
{
    long long g = (long long)blockIdx.x * 256 + threadIdx.x;
    int node = (int)(g >> 4);
    int q    = (int)(g & 15);          // lane handles 8 bf16 = 16 B
    if (node >= N) return;

    float acc[8];
    ushort8 r;

    // ---- segment A ----
    #pragma unroll
    for (int t = 0; t < 8; ++t) acc[t] = 0.f;
    {
        int j = rpa[node], e = rpa[node + 1];
        for (; j + 4 <= e; j += 4) {
            int c0 = col[j], c1 = col[j+1], c2 = col[j+2], c3 = col[j+3];
            ushort8 v0 = *(const ushort8*)(xa + (size_t)c0 * DD + q * 8);
            ushort8 v1 = *(const ushort8*)(xa + (size_t)c1 * DD + q * 8);
            ushort8 v2 = *(const ushort8*)(xa + (size_t)c2 * DD + q * 8);
            ushort8 v3 = *(const ushort8*)(xa + (size_t)c3 * DD + q * 8);
            #pragma unroll
            for (int t = 0; t < 8; ++t)
                acc[t] += (b2f(v0[t]) + b2f(v1[t])) + (b2f(v2[t]) + b2f(v3[t]));
        }
        for (; j < e; ++j) {
            ushort8 v = *(const ushort8*)(xa + (size_t)col[j] * DD + q * 8);
            #pragma unroll
            for (int t = 0; t < 8; ++t) acc[t] += b2f(v[t]);
        }
    }
    float sc = inva[node];
    #pragma unroll
    for (int t = 0; t < 8; ++t) r[t] = f2b(acc[t] * sc);
    *(ushort8*)(agg0 + (size_t)node * DD + q * 8) = r;

    // ---- segment B ----
    #pragma unroll
    for (int t = 0; t < 8; ++t) acc[t] = 0.f;
    {
        int j = rpb[node], e = rpb[node + 1];
        for (; j + 4 <= e; j += 4) {
            int c0 = col[j], c1 = col[j+1], c2 = col[j+2], c3 = col[j+3];
            ushort8 v0 = *(const ushort8*)(xb + (size_t)c0 * DD + q * 8);
            ushort8 v1 = *(const ushort8*)(xb + (size_t)c1 * DD + q * 8);
            ushort8 v2 = *(const ushort8*)(xb + (size_t)c2 * DD + q * 8);
            ushort8 v3 = *(const ushort8*)(xb + (size_t)c3 * DD + q * 8);
            #pragma unroll
            for (int t = 0; t < 8; ++t)
                acc[t] += (b2f(v0[t]) + b2f(v1[t])) + (b2f(v2[t]) + b2f(v3[t]));
        }
        for (; j < e; ++j) {
            ushort8 v = *(const ushort8*)(xb + (size_t)col[j] * DD + q * 8);
            #pragma unroll
            for (int t = 0; t < 8; ++t) acc[t] += b2f(v[t]);
        }
    }
    sc = invb[node];
    #pragma unroll
    for (int t = 0; t < 8; ++t) r[t] = f2b(acc[t] * sc);
    *(ushort8*)(agg1 + (size_t)node * DD + q * 8) = r;
}

// ---------------- MFMA GEMM: out = [agg_a | agg_b | x](bf16) @ WT^T + bc (+relu) --------
__global__ __launch_bounds__(256) void gemm_mfma(
    const unsigned short* __restrict__ agg_a, const unsigned short* __restrict__ agg_b,
    const unsigned short* __restrict__ xs, const unsigned short* __restrict__ WT,
    const float* __restrict__ bias, void* __restrict__ outp,
    int relu, int write_f32, int N)
{
    __shared__ unsigned short As[BM * LDK];      // 50176 B
    const int tid  = threadIdx.x;
    const int row0 = blockIdx.x * BM;

    // stage A tile: 64 rows x 48 chunks(16B) = 3072 chunks, 12/thread, coalesced
    #pragma unroll
    for (int it = 0; it < 12; ++it) {
        int i   = tid + it * 256;
        int row = i / 48;
        int c   = i - row * 48;
        int seg = c >> 4;
        int kk  = c & 15;
        int rg  = row0 + row;
        if (rg >= N) rg = N - 1;
        const unsigned short* src = (seg == 0) ? agg_a : (seg == 1) ? agg_b : xs;
        uint4 v = *(const uint4*)(src + (size_t)rg * DD + kk * 8);
        *(uint4*)(&As[row * LDK + seg * 128 + kk * 8]) = v;
    }
    __syncthreads();

    const int wave = tid >> 6;
    const int lane = tid & 63;
    const int wr = (wave >> 1) * 32;         // 0 / 32
    const int wc = (wave & 1) * 64;          // 0 / 64
    const int fr = lane & 15;
    const int fk = (lane >> 4) * 8;

    floatx4 acc[2][4] = {};
    const unsigned short* wbase = WT + (size_t)(wc + fr) * KTOT + fk;

    short8 a0c, a1c, a0n, a1n, bC[4], bN[4];
    a0c = *(const short8*)(&As[(wr      + fr) * LDK + fk]);
    a1c = *(const short8*)(&As[(wr + 16 + fr) * LDK + fk]);
    #pragma unroll
    for (int c = 0; c < 4; ++c) bC[c] = *(const short8*)(wbase + (size_t)c * 16 * KTOT);

    #pragma unroll
    for (int ks = 0; ks < 12; ++ks) {
        if (ks < 11) {
            int k1 = (ks + 1) * 32;
            a0n = *(const short8*)(&As[(wr      + fr) * LDK + k1 + fk]);
            a1n = *(const short8*)(&As[(wr + 16 + fr) * LDK + k1 + fk]);
            #pragma unroll
            for (int c = 0; c < 4; ++c) bN[c] = *(const short8*)(wbase + (size_t)c * 16 * KTOT + k1);
        }
        #pragma unroll
        for (int c = 0; c < 4; ++c) {
            acc[0][c] = __builtin_amdgcn_mfma_f32_16x16x32_bf16(a0c, bC[c], acc[0][c], 0, 0, 0);
            acc[1][c] = __builtin_amdgcn_mfma_f32_16x16x32_bf16(a1c, bC[c], acc[1][c], 0, 0, 0);
        }
        a0c = a0n; a1c = a1n;
        #pragma unroll
        for (int c = 0; c < 4; ++c) bC[c] = bN[c];
    }

    // epilogue: col = wc + c*16 + (lane&15), row = wr + m*16 + (lane>>4)*4 + i  [m89 layout]
    float* outf = (float*)outp;
    unsigned short* outb = (unsigned short*)outp;
    const int rb = (lane >> 4) * 4;
    #pragma unroll
    for (int c = 0; c < 4; ++c) {
        int ocol = wc + c * 16 + fr;
        float bb = bias[ocol];
        #pragma unroll
        for (int m = 0; m < 2; ++m) {
            #pragma unroll
            for (int i = 0; i < 4; ++i) {
                int orow = row0 + wr + m * 16 + rb + i;
                if (orow >= N) continue;
                float v = acc[m][c][i] + bb;
                if (relu) v = fmaxf(v, 0.f);
                if (write_f32) outf[(size_t)orow * DD + ocol] = v;
                else           outb[(size_t)orow * DD + ocol] = f2b(v);
            }
        }
    }
}

extern "C" void kernel_launch(void* const* d_in, const int* in_sizes, int n_in,
                              void* d_out, int out_size, void* d_ws, size_t ws_size,
                              hipStream_t stream)
{
    const float* x_d = (const float*)d_in[0];
    const float* x_m = (const float*)d_in[1];
    const float* Wl  = (const float*)d_in[6];
    const float* bl  = (const float*)d_in[7];
    const float* Wr  = (const float*)d_in[8];
    float* out = (float*)d_out;

    const int N    = in_sizes[0] / DD;
    const int E_dd = in_sizes[2] / 2;
    const int E_mm = in_sizes[3] / 2;
    const int E_dm = in_sizes[4] / 2;
    const int E_md = in_sizes[5] / 2;
    const int E_tot = E_dd + E_md + E_mm + E_dm;
    const int n4 = 4 * N;
    const int nb = (n4 + BS - 1) >> BS_BITS;

    char* ws = (char*)d_ws;
    size_t off = 0;
    auto alloc = [&](size_t bytes) {
        void* p = ws + off;
        off += (bytes + 255) & ~(size_t)255;
        return p;
    };
    unsigned short* xb_d  = (unsigned short*)alloc((size_t)N * DD * 2);
    unsigned short* xb_m  = (unsigned short*)alloc((size_t)N * DD * 2);
    unsigned short* hb_d  = (unsigned short*)alloc((size_t)N * DD * 2);
    unsigned short* hb_m  = (unsigned short*)alloc((size_t)N * DD * 2);
    unsigned short* agg0  = (unsigned short*)alloc((size_t)N * DD * 2);
    unsigned short* agg1  = (unsigned short*)alloc((size_t)N * DD * 2);
    float* inv_all = (float*)alloc((size_t)n4 * 4);
    int*   rp_all  = (int*)  alloc((size_t)(n4 + 1) * 4);
    int*   bucket_fill = (int*)alloc((size_t)NBMAX * 4);
    int*   bucket_base = (int*)alloc((size_t)NBMAX * 4);
    unsigned short* WT = (unsigned short*)alloc((size_t)2 * 2 * DD * KTOT * 2);
    float* bc      = (float*)alloc((size_t)512 * 4);
    unsigned* stage = (unsigned*)alloc((size_t)nb * CAP * 4);
    int*   col     = (int*)alloc((size_t)E_tot * 4);
    unsigned long long* ovf = (unsigned long long*)alloc((size_t)(1 << 18) * 8);
    int*   ovf_cnt = (int*)alloc(256);
    int*   flag    = (int*)alloc(256);

    const float* inv_dd = inv_all, *inv_md = inv_all + N, *inv_mm = inv_all + 2*N, *inv_dm = inv_all + 3*N;
    const int* rp_dd  = rp_all,   *rp_md  = rp_all + N,  *rp_mm  = rp_all + 2*N,  *rp_dm  = rp_all + 3*N;

    // ---- edge dtype probe ----
    hipMemsetAsync(flag, 0, 256, stream);
    detect_i32<<<4, 256, 0, stream>>>((const int*)d_in[2], 1024, flag);

    // ---- x -> bf16 ----
    const int n8 = N * DD / 8;
    cvt_bf16<<<(n8 + 255) / 256, 256, 0, stream>>>(x_d, xb_d, n8);
    cvt_bf16<<<(n8 + 255) / 256, 256, 0, stream>>>(x_m, xb_m, n8);

    // ---- CSR build: bin -> bucket scan -> per-bucket count/scan/fill ----
    hipMemsetAsync(bucket_fill, 0, (size_t)NBMAX * 4, stream);
    hipMemsetAsync(ovf_cnt, 0, 256, stream);
    const int nchunks = (E_tot + CHUNK - 1) / CHUNK;
    bin_edges<<<nchunks, 512, 0, stream>>>(
        d_in[2], d_in[5], d_in[3], d_in[4], E_dd, E_md, E_mm, E_dm,
        flag, bucket_fill, stage, ovf, ovf_cnt, N, nb);
    scan_buckets<<<1, 512, 0, stream>>>(bucket_fill, nb, bucket_base);
    fill_from_stage<<<nb, 512, 0, stream>>>(
        stage, bucket_fill, bucket_base, ovf, ovf_cnt, rp_all, inv_all, col, n4);

    build_wcomb<<<(2 * 2 * DD * KTOT + 255) / 256, 256, 0, stream>>>(Wl, bl, Wr, WT, bc);

    const int agg_grid  = (int)(((size_t)N * 16 + 255) / 256);
    const int gemm_grid = (N + BM - 1) / BM;
    const unsigned short* xd_cur = xb_d;
    const unsigned short* xm_cur = xb_m;
    for (int l = 0; l < 2; ++l) {
        int relu = (l == 0);
        int wf32 = (l == 1);
        void* od = (l == 1) ? (void*)out : (void*)hb_d;
        void* om = (l == 1) ? (void*)(out + (size_t)N * DD) : (void*)hb_m;

        // dst d: seg0 = dd (gather xd), seg1 = md (gather xm), seg2 = xd
        aggregate2<<<agg_grid, 256, 0, stream>>>(
            xd_cur, rp_dd, inv_dd, xm_cur, rp_md, inv_md, col, agg0, agg1, N);
        gemm_mfma<<<gemm_grid, 256, 0, stream>>>(
            agg0, agg1, xd_cur, WT + (size_t)(l * 2 + 0) * DD * KTOT,
            bc + (l * 2 + 0) * DD, od, relu, wf32, N);

        // dst m: seg0 = mm (gather xm), seg1 = dm (gather xd), seg2 = xm
        aggregate2<<<agg_grid, 256, 0, stream>>>(
            xm_cur, rp_mm, inv_mm, xd_cur, rp_dm, inv_dm, col, agg0, agg1, N);
        gemm_mfma<<<gemm_grid, 256, 0, stream>>>(
            agg0, agg1, xm_cur, WT + (size_t)(l * 2 + 1) * DD * KTOT,
            bc + (l * 2 + 1) * DD, om, relu, wf32, N);

        xd_cur = hb_d;
        xm_cur = hb_m;
    }
}

// Round 12
// 455.882 us; speedup vs baseline: 2.2294x; 1.2043x over previous
//
#include <hip/hip_runtime.h>

#define DD 128
#define KTOT 384
#define BM 64
#define BS_BITS 10
#define BS 1024          // nodes per bucket
#define NBMAX 512        // max buckets (4N <= 512K)
#define CHUNK 2048       // edges per bin_edges block
#define CAP 12288        // stage slots per bucket (max expected ~10.6K)

typedef __attribute__((ext_vector_type(8))) short short8;
typedef __attribute__((ext_vector_type(8))) unsigned short ushort8;
typedef __attribute__((ext_vector_type(4))) float floatx4;

__device__ __forceinline__ unsigned short f2b(float f) {
    union { float f; unsigned u; } v; v.f = f;
    return (unsigned short)((v.u + 0x7fffu + ((v.u >> 16) & 1u)) >> 16);
}
__device__ __forceinline__ float b2f(unsigned short u) {
    union { unsigned u; float f; } v; v.u = ((unsigned)u) << 16;
    return v.f;
}

// ---------------- edge dtype probe: int64 arrays have all-zero odd int32 words ----------
__global__ __launch_bounds__(256) void detect_i32(const int* __restrict__ p, int nodd,
                                                  int* __restrict__ flag)
{
    int i = blockIdx.x * 256 + threadIdx.x;
    if (i < nodd && p[2 * i + 1] != 0) atomicOr(flag, 1);
}

// ---------------- x -> bf16 (row-major) ----------------
__global__ __launch_bounds__(256) void cvt_bf16(const float* __restrict__ in,
                                                unsigned short* __restrict__ out, int n8)
{
    int i = blockIdx.x * 256 + threadIdx.x;
    if (i >= n8) return;
    float4 v0 = *(const float4*)(in + (size_t)i * 8);
    float4 v1 = *(const float4*)(in + (size_t)i * 8 + 4);
    ushort8 r;
    r[0]=f2b(v0.x); r[1]=f2b(v0.y); r[2]=f2b(v0.z); r[3]=f2b(v0.w);
    r[4]=f2b(v1.x); r[5]=f2b(v1.y); r[6]=f2b(v1.z); r[7]=f2b(v1.w);
    *(ushort8*)(out + (size_t)i * 8) = r;
}

// ---------------- weight prep: WT_t = combined W^T in fragment-tiled layout ------------
// per (l,dst) block of 49152 elems: [ct16][k32][lane=(fk8<<4)|frc][8]
__global__ __launch_bounds__(256) void build_wcomb(
    const float* __restrict__ Wl, const float* __restrict__ bl,
    const float* __restrict__ Wr, unsigned short* __restrict__ WTt, float* __restrict__ bc)
{
    int idx = blockIdx.x * 256 + threadIdx.x;
    if (idx < 2 * 2 * DD * KTOT) {
        int k  = idx % KTOT;
        int t1 = idx / KTOT;
        int i  = t1 & 127;
        int t2 = t1 >> 7;
        int dt = t2 & 1;      // 0 = dst d, 1 = dst m
        int l  = t2 >> 1;
        int ta = dt ? 1 : 0;  // d: dd(0), m: mm(1)
        int tb = dt ? 2 : 3;  // d: md(3), m: dm(2)
        float v;
        if (k < 128) {
            v = Wl[(((size_t)(l * 4 + ta) * 128 + i) << 7) + k];
        } else if (k < 256) {
            v = Wl[(((size_t)(l * 4 + tb) * 128 + i) << 7) + (k - 128)];
        } else {
            int kk = k - 256;
            v = Wr[(((size_t)(l * 4 + ta) * 128 + i) << 7) + kk]
              + Wr[(((size_t)(l * 4 + tb) * 128 + i) << 7) + kk];
        }
        // tiled index: ct16 = i>>4, frc = i&15, k32 = k>>5, fk8 = (k>>3)&3, e = k&7
        int tidx = ((((i >> 4) * 12 + (k >> 5)) * 64) + (((k >> 3) & 3) * 16 + (i & 15))) * 8
                 + (k & 7);
        WTt[(size_t)t2 * (DD * KTOT) + tidx] = f2b(v);
    }
    if (idx < 512) {
        int i  = idx & 127;
        int t2 = idx >> 7;
        int dt = t2 & 1;
        int l  = t2 >> 1;
        int ta = dt ? 1 : 0;
        int tb = dt ? 2 : 3;
        bc[idx] = bl[(l * 4 + ta) * 128 + i] + bl[(l * 4 + tb) * 128 + i];
    }
}

// ---------------- phase A: LDS-binned edge staging, fixed-CAP bucket regions ----------
__global__ __launch_bounds__(512) void bin_edges(
    const void* __restrict__ e0, const void* __restrict__ e1,
    const void* __restrict__ e2, const void* __restrict__ e3,
    int E0, int E1, int E2, int E3,
    const int* __restrict__ flag, int* __restrict__ bucket_fill,
    unsigned* __restrict__ stage,
    unsigned long long* __restrict__ ovf, int* __restrict__ ovf_cnt,
    int N, int nb)
{
    __shared__ unsigned sb_pack[CHUNK];
    __shared__ unsigned short sb_b[CHUNK];
    __shared__ int hist[NBMAX];
    __shared__ int offs[NBMAX];
    __shared__ int base[NBMAX];

    const int tid   = threadIdx.x;
    const int E_tot = E0 + E1 + E2 + E3;
    const int e_bas = blockIdx.x * CHUNK;
    const int e_end = min(e_bas + CHUNK, E_tot);
    const int cnt_e = e_end - e_bas;
    const int isI32 = *flag;

    for (int i = tid; i < nb; i += 512) hist[i] = 0;
    __syncthreads();

    unsigned my_pack[4];
    int my_b[4], my_r[4];
    #pragma unroll
    for (int u = 0; u < 4; ++u) {
        my_b[u] = -1;
        int e = e_bas + tid + u * 512;
        if (e < e_end) {
            const void* ep; int El, type, le = e;
            if (le < E0)              { ep = e0; El = E0; type = 0; }
            else if ((le -= E0) < E1) { ep = e1; El = E1; type = 1; }
            else if ((le -= E1) < E2) { ep = e2; El = E2; type = 2; }
            else                      { le -= E2; ep = e3; El = E3; type = 3; }
            int s, d;
            if (isI32) {
                s = ((const int*)ep)[le];
                d = ((const int*)ep)[(size_t)El + le];
            } else {
                s = (int)((const long long*)ep)[le];
                d = (int)((const long long*)ep)[(size_t)El + le];
            }
            int gnode = type * N + d;
            int b = gnode >> BS_BITS;
            my_b[u]    = b;
            my_pack[u] = ((unsigned)s << BS_BITS) | (unsigned)(gnode & (BS - 1));
            my_r[u]    = atomicAdd(&hist[b], 1);
        }
    }
    __syncthreads();

    offs[tid] = (tid < nb) ? hist[tid] : 0;
    __syncthreads();
    for (int d = 1; d < 512; d <<= 1) {
        int v = (tid >= d) ? offs[tid - d] : 0;
        __syncthreads();
        offs[tid] += v;
        __syncthreads();
    }
    if (tid < nb) {
        offs[tid] -= hist[tid];                              // exclusive
        base[tid] = hist[tid] ? atomicAdd(&bucket_fill[tid], hist[tid]) : 0;
    }
    __syncthreads();

    #pragma unroll
    for (int u = 0; u < 4; ++u) {
        if (my_b[u] >= 0) {
            int pos = offs[my_b[u]] + my_r[u];
            sb_pack[pos] = my_pack[u];
            sb_b[pos]    = (unsigned short)my_b[u];
        }
    }
    __syncthreads();

    for (int pos = tid; pos < cnt_e; pos += 512) {
        int b = sb_b[pos];
        unsigned p = sb_pack[pos];
        int idx = base[b] + (pos - offs[b]);
        if (idx < CAP) {
            stage[(size_t)b * CAP + idx] = p;
        } else {                                             // overflow (expected: never)
            int k = atomicAdd(ovf_cnt, 1);
            int gnode = (b << BS_BITS) | (int)(p & (BS - 1));
            ovf[k] = ((unsigned long long)(unsigned)gnode << 32) | (p >> BS_BITS);
        }
    }
}

// ---------------- exclusive scan over bucket totals (1 block) ----------------
__global__ __launch_bounds__(512) void scan_buckets(const int* __restrict__ fill, int nb,
                                                    int* __restrict__ base)
{
    __shared__ int s[512];
    const int tid = threadIdx.x;
    int v = (tid < nb) ? fill[tid] : 0;
    s[tid] = v;
    __syncthreads();
    for (int d = 1; d < 512; d <<= 1) {
        int u = (tid >= d) ? s[tid - d] : 0;
        __syncthreads();
        s[tid] += u;
        __syncthreads();
    }
    if (tid < nb) base[tid] = s[tid] - v;    // exclusive
}

// ---------------- phase B: per-bucket count + scan + rp/inv + CSR fill ----------------
__global__ __launch_bounds__(512) void fill_from_stage(
    const unsigned* __restrict__ stage, const int* __restrict__ bucket_fill,
    const int* __restrict__ bucket_base,
    const unsigned long long* __restrict__ ovf, const int* __restrict__ ovf_cnt,
    int* __restrict__ rp_all, float* __restrict__ inv_all, int* __restrict__ col, int n4)
{
    __shared__ int cl[BS];     // counts, later cursors
    __shared__ int rl[BS];     // exclusive scan
    __shared__ int w[512];

    const int tid   = threadIdx.x;
    const int b     = blockIdx.x;
    const int node0 = b << BS_BITS;
    const int nn    = min(BS, n4 - node0);

    cl[tid] = 0; cl[tid + 512] = 0;
    __syncthreads();

    const int total  = bucket_fill[b];
    const int nstage = min(total, CAP);
    const unsigned* st = stage + (size_t)b * CAP;
    const int novf = *ovf_cnt;

    for (int j = tid; j < nstage; j += 512)
        atomicAdd(&cl[st[j] & (BS - 1)], 1);
    for (int k = tid; k < novf; k += 512) {
        int g = (int)(ovf[k] >> 32);
        if (g >= node0 && g < node0 + nn) atomicAdd(&cl[g - node0], 1);
    }
    __syncthreads();

    int a0 = cl[2 * tid], a1 = cl[2 * tid + 1];
    w[tid] = a0 + a1;
    __syncthreads();
    for (int d = 1; d < 512; d <<= 1) {
        int v = (tid >= d) ? w[tid - d] : 0;
        __syncthreads();
        w[tid] += v;
        __syncthreads();
    }
    int excl = w[tid] - a0 - a1;
    rl[2 * tid]     = excl;
    rl[2 * tid + 1] = excl + a0;
    __syncthreads();

    const int gbase = bucket_base[b];
    for (int i = tid; i < nn; i += 512) {
        rp_all[node0 + i] = gbase + rl[i];
        inv_all[node0 + i] = 1.0f / (float)max(cl[i], 1);
    }
    if (b == gridDim.x - 1 && tid == 0) rp_all[n4] = gbase + total;
    __syncthreads();

    for (int i = tid; i < BS; i += 512) cl[i] = gbase + rl[i];
    __syncthreads();

    for (int j = tid; j < nstage; j += 512) {
        unsigned p = st[j];
        int slot = atomicAdd(&cl[p & (BS - 1)], 1);
        col[slot] = (int)(p >> BS_BITS);
    }
    for (int k = tid; k < novf; k += 512) {
        unsigned long long p = ovf[k];
        int g = (int)(p >> 32);
        if (g >= node0 && g < node0 + nn) {
            int slot = atomicAdd(&cl[g - node0], 1);
            col[slot] = (int)(p & 0xffffffffu);
        }
    }
}

// ---------------- gather-aggregate into fragment-tiled A_t + x copy ----------------
// A_t tile layout: [r16][k32 0..11][lane=(fk8<<4)|fr][8] bf16; k32 0-3 = mean_self,
// 4-7 = mean_other, 8-11 = xself copy. Thread = (node, q); fr=node&15, k32off=q>>2,
// in-tile offset = ((q&3)*16 + fr)*8.
__global__ __launch_bounds__(256) void aggregate2(
    const unsigned short* __restrict__ xa, const int* __restrict__ rpa,
    const float* __restrict__ inva,
    const unsigned short* __restrict__ xb, const int* __restrict__ rpb,
    const float* __restrict__ invb,
    const int* __restrict__ col, unsigned short* __restrict__ At, int N)
{
    long long g = (long long)blockIdx.x * 256 + threadIdx.x;
    int node = (int)(g >> 4);
    int q    = (int)(g & 15);          // lane handles 8 bf16 = 16 B
    if (node >= N) return;

    const int r16 = node >> 4;
    const int fr  = node & 15;
    unsigned short* tbase = At + ((size_t)r16 * 12 + (q >> 2)) * 512 + ((q & 3) * 16 + fr) * 8;

    float acc[8];
    ushort8 r;

    // ---- segment A (self) -> k32 0..3 ----
    #pragma unroll
    for (int t = 0; t < 8; ++t) acc[t] = 0.f;
    {
        int j = rpa[node], e = rpa[node + 1];
        for (; j + 4 <= e; j += 4) {
            int c0 = col[j], c1 = col[j+1], c2 = col[j+2], c3 = col[j+3];
            ushort8 v0 = *(const ushort8*)(xa + (size_t)c0 * DD + q * 8);
            ushort8 v1 = *(const ushort8*)(xa + (size_t)c1 * DD + q * 8);
            ushort8 v2 = *(const ushort8*)(xa + (size_t)c2 * DD + q * 8);
            ushort8 v3 = *(const ushort8*)(xa + (size_t)c3 * DD + q * 8);
            #pragma unroll
            for (int t = 0; t < 8; ++t)
                acc[t] += (b2f(v0[t]) + b2f(v1[t])) + (b2f(v2[t]) + b2f(v3[t]));
        }
        for (; j < e; ++j) {
            ushort8 v = *(const ushort8*)(xa + (size_t)col[j] * DD + q * 8);
            #pragma unroll
            for (int t = 0; t < 8; ++t) acc[t] += b2f(v[t]);
        }
    }
    float sc = inva[node];
    #pragma unroll
    for (int t = 0; t < 8; ++t) r[t] = f2b(acc[t] * sc);
    *(ushort8*)(tbase) = r;

    // ---- segment B (other) -> k32 4..7 ----
    #pragma unroll
    for (int t = 0; t < 8; ++t) acc[t] = 0.f;
    {
        int j = rpb[node], e = rpb[node + 1];
        for (; j + 4 <= e; j += 4) {
            int c0 = col[j], c1 = col[j+1], c2 = col[j+2], c3 = col[j+3];
            ushort8 v0 = *(const ushort8*)(xb + (size_t)c0 * DD + q * 8);
            ushort8 v1 = *(const ushort8*)(xb + (size_t)c1 * DD + q * 8);
            ushort8 v2 = *(const ushort8*)(xb + (size_t)c2 * DD + q * 8);
            ushort8 v3 = *(const ushort8*)(xb + (size_t)c3 * DD + q * 8);
            #pragma unroll
            for (int t = 0; t < 8; ++t)
                acc[t] += (b2f(v0[t]) + b2f(v1[t])) + (b2f(v2[t]) + b2f(v3[t]));
        }
        for (; j < e; ++j) {
            ushort8 v = *(const ushort8*)(xb + (size_t)col[j] * DD + q * 8);
            #pragma unroll
            for (int t = 0; t < 8; ++t) acc[t] += b2f(v[t]);
        }
    }
    sc = invb[node];
    #pragma unroll
    for (int t = 0; t < 8; ++t) r[t] = f2b(acc[t] * sc);
    *(ushort8*)(tbase + 4 * 512) = r;

    // ---- xself copy -> k32 8..11 ----
    ushort8 xv = *(const ushort8*)(xa + (size_t)node * DD + q * 8);
    *(ushort8*)(tbase + 8 * 512) = xv;
}

// ---------------- MFMA GEMM, LDS-free: A_t (tiled) @ WT_t (tiled) + bc (+relu) ---------
__global__ __launch_bounds__(256) void gemm_mfma(
    const unsigned short* __restrict__ At, const unsigned short* __restrict__ WTt,
    const float* __restrict__ bias, void* __restrict__ outp,
    int relu, int write_f32, int N)
{
    const int tid  = threadIdx.x;
    const int row0 = blockIdx.x * BM;
    const int M16  = (N + 15) >> 4;

    const int wave = tid >> 6;
    const int lane = tid & 63;
    const int wr = (wave >> 1) * 32;         // 0 / 32
    const int wc = (wave & 1) * 64;          // 0 / 64

    int r16a = (row0 >> 4) + (wave >> 1) * 2;
    int r16b = r16a + 1;
    if (r16a > M16 - 1) r16a = M16 - 1;
    if (r16b > M16 - 1) r16b = M16 - 1;

    const unsigned short* Abase0 = At + (size_t)r16a * 12 * 512 + lane * 8;
    const unsigned short* Abase1 = At + (size_t)r16b * 12 * 512 + lane * 8;
    const unsigned short* Wbase  = WTt + (size_t)(wc >> 4) * 12 * 512 + lane * 8;

    floatx4 acc[2][4] = {};

    short8 a0c, a1c, a0n, a1n, bC[4], bN[4];
    a0c = *(const short8*)(Abase0);
    a1c = *(const short8*)(Abase1);
    #pragma unroll
    for (int c = 0; c < 4; ++c) bC[c] = *(const short8*)(Wbase + (size_t)c * 12 * 512);

    #pragma unroll
    for (int ks = 0; ks < 12; ++ks) {
        if (ks < 11) {
            int o = (ks + 1) * 512;
            a0n = *(const short8*)(Abase0 + o);
            a1n = *(const short8*)(Abase1 + o);
            #pragma unroll
            for (int c = 0; c < 4; ++c) bN[c] = *(const short8*)(Wbase + (size_t)c * 12 * 512 + o);
        }
        #pragma unroll
        for (int c = 0; c < 4; ++c) {
            acc[0][c] = __builtin_amdgcn_mfma_f32_16x16x32_bf16(a0c, bC[c], acc[0][c], 0, 0, 0);
            acc[1][c] = __builtin_amdgcn_mfma_f32_16x16x32_bf16(a1c, bC[c], acc[1][c], 0, 0, 0);
        }
        a0c = a0n; a1c = a1n;
        #pragma unroll
        for (int c = 0; c < 4; ++c) bC[c] = bN[c];
    }

    // epilogue: col = wc + c*16 + (lane&15), row = wr + m*16 + (lane>>4)*4 + i  [m89 layout]
    float* outf = (float*)outp;
    unsigned short* outb = (unsigned short*)outp;
    const int fr = lane & 15;
    const int rb = (lane >> 4) * 4;
    #pragma unroll
    for (int c = 0; c < 4; ++c) {
        int ocol = wc + c * 16 + fr;
        float bb = bias[ocol];
        #pragma unroll
        for (int m = 0; m < 2; ++m) {
            #pragma unroll
            for (int i = 0; i < 4; ++i) {
                int orow = row0 + wr + m * 16 + rb + i;
                if (orow >= N) continue;
                float v = acc[m][c][i] + bb;
                if (relu) v = fmaxf(v, 0.f);
                if (write_f32) outf[(size_t)orow * DD + ocol] = v;
                else           outb[(size_t)orow * DD + ocol] = f2b(v);
            }
        }
    }
}

extern "C" void kernel_launch(void* const* d_in, const int* in_sizes, int n_in,
                              void* d_out, int out_size, void* d_ws, size_t ws_size,
                              hipStream_t stream)
{
    const float* x_d = (const float*)d_in[0];
    const float* x_m = (const float*)d_in[1];
    const float* Wl  = (const float*)d_in[6];
    const float* bl  = (const float*)d_in[7];
    const float* Wr  = (const float*)d_in[8];
    float* out = (float*)d_out;

    const int N    = in_sizes[0] / DD;
    const int E_dd = in_sizes[2] / 2;
    const int E_mm = in_sizes[3] / 2;
    const int E_dm = in_sizes[4] / 2;
    const int E_md = in_sizes[5] / 2;
    const int E_tot = E_dd + E_md + E_mm + E_dm;
    const int n4 = 4 * N;
    const int nb = (n4 + BS - 1) >> BS_BITS;
    const int M16 = (N + 15) >> 4;

    char* ws = (char*)d_ws;
    size_t off = 0;
    auto alloc = [&](size_t bytes) {
        void* p = ws + off;
        off += (bytes + 255) & ~(size_t)255;
        return p;
    };
    unsigned short* xb_d  = (unsigned short*)alloc((size_t)N * DD * 2);
    unsigned short* xb_m  = (unsigned short*)alloc((size_t)N * DD * 2);
    unsigned short* hb_d  = (unsigned short*)alloc((size_t)N * DD * 2);
    unsigned short* hb_m  = (unsigned short*)alloc((size_t)N * DD * 2);
    unsigned short* At    = (unsigned short*)alloc((size_t)M16 * 12 * 512 * 2);
    float* inv_all = (float*)alloc((size_t)n4 * 4);
    int*   rp_all  = (int*)  alloc((size_t)(n4 + 1) * 4);
    int*   bucket_fill = (int*)alloc((size_t)NBMAX * 4);
    int*   bucket_base = (int*)alloc((size_t)NBMAX * 4);
    unsigned short* WTt = (unsigned short*)alloc((size_t)2 * 2 * DD * KTOT * 2);
    float* bc      = (float*)alloc((size_t)512 * 4);
    unsigned* stage = (unsigned*)alloc((size_t)nb * CAP * 4);
    int*   col     = (int*)alloc((size_t)E_tot * 4);
    unsigned long long* ovf = (unsigned long long*)alloc((size_t)(1 << 18) * 8);
    int*   ovf_cnt = (int*)alloc(256);
    int*   flag    = (int*)alloc(256);

    const float* inv_dd = inv_all, *inv_md = inv_all + N, *inv_mm = inv_all + 2*N, *inv_dm = inv_all + 3*N;
    const int* rp_dd  = rp_all,   *rp_md  = rp_all + N,  *rp_mm  = rp_all + 2*N,  *rp_dm  = rp_all + 3*N;

    // ---- edge dtype probe ----
    hipMemsetAsync(flag, 0, 256, stream);
    detect_i32<<<4, 256, 0, stream>>>((const int*)d_in[2], 1024, flag);

    // ---- x -> bf16 (row-major, gather source + aggregate2 copy source) ----
    const int n8 = N * DD / 8;
    cvt_bf16<<<(n8 + 255) / 256, 256, 0, stream>>>(x_d, xb_d, n8);
    cvt_bf16<<<(n8 + 255) / 256, 256, 0, stream>>>(x_m, xb_m, n8);

    // ---- CSR build: bin -> bucket scan -> per-bucket count/scan/fill ----
    hipMemsetAsync(bucket_fill, 0, (size_t)NBMAX * 4, stream);
    hipMemsetAsync(ovf_cnt, 0, 256, stream);
    const int nchunks = (E_tot + CHUNK - 1) / CHUNK;
    bin_edges<<<nchunks, 512, 0, stream>>>(
        d_in[2], d_in[5], d_in[3], d_in[4], E_dd, E_md, E_mm, E_dm,
        flag, bucket_fill, stage, ovf, ovf_cnt, N, nb);
    scan_buckets<<<1, 512, 0, stream>>>(bucket_fill, nb, bucket_base);
    fill_from_stage<<<nb, 512, 0, stream>>>(
        stage, bucket_fill, bucket_base, ovf, ovf_cnt, rp_all, inv_all, col, n4);

    build_wcomb<<<(2 * 2 * DD * KTOT + 255) / 256, 256, 0, stream>>>(Wl, bl, Wr, WTt, bc);

    const int agg_grid  = (int)(((size_t)N * 16 + 255) / 256);
    const int gemm_grid = (N + BM - 1) / BM;
    const unsigned short* xd_cur = xb_d;
    const unsigned short* xm_cur = xb_m;
    for (int l = 0; l < 2; ++l) {
        int relu = (l == 0);
        int wf32 = (l == 1);
        void* od = (l == 1) ? (void*)out : (void*)hb_d;
        void* om = (l == 1) ? (void*)(out + (size_t)N * DD) : (void*)hb_m;

        // dst d: self = xd (agg via rp_dd), other = xm (agg via rp_md)
        aggregate2<<<agg_grid, 256, 0, stream>>>(
            xd_cur, rp_dd, inv_dd, xm_cur, rp_md, inv_md, col, At, N);
        gemm_mfma<<<gemm_grid, 256, 0, stream>>>(
            At, WTt + (size_t)(l * 2 + 0) * DD * KTOT,
            bc + (l * 2 + 0) * DD, od, relu, wf32, N);

        // dst m: self = xm (agg via rp_mm), other = xd (agg via rp_dm)
        aggregate2<<<agg_grid, 256, 0, stream>>>(
            xm_cur, rp_mm, inv_mm, xd_cur, rp_dm, inv_dm, col, At, N);
        gemm_mfma<<<gemm_grid, 256, 0, stream>>>(
            At, WTt + (size_t)(l * 2 + 1) * DD * KTOT,
            bc + (l * 2 + 1) * DD, om, relu, wf32, N);

        xd_cur = hb_d;
        xm_cur = hb_m;
    }
}

// Round 13
// 428.800 us; speedup vs baseline: 2.3702x; 1.0632x over previous
//
#include <hip/hip_runtime.h>

#define DD 128
#define KTOT 384
#define BM 64
#define BS_BITS 10
#define BS 1024          // nodes per bucket
#define NBMAX 512        // max buckets (4N <= 512K)
#define CHUNK 2048       // edges per bin_edges block
#define CAP 12288        // stage slots per bucket (max expected ~10.6K)

typedef __attribute__((ext_vector_type(8))) short short8;
typedef __attribute__((ext_vector_type(8))) unsigned short ushort8;
typedef __attribute__((ext_vector_type(4))) float floatx4;

__device__ __forceinline__ unsigned short f2b(float f) {
    union { float f; unsigned u; } v; v.f = f;
    return (unsigned short)((v.u + 0x7fffu + ((v.u >> 16) & 1u)) >> 16);
}
__device__ __forceinline__ float b2f(unsigned short u) {
    union { unsigned u; float f; } v; v.u = ((unsigned)u) << 16;
    return v.f;
}

// ---------------- edge dtype probe: int64 arrays have all-zero odd int32 words ----------
__global__ __launch_bounds__(256) void detect_i32(const int* __restrict__ p, int nodd,
                                                  int* __restrict__ flag)
{
    int i = blockIdx.x * 256 + threadIdx.x;
    if (i < nodd && p[2 * i + 1] != 0) atomicOr(flag, 1);
}

// ---------------- x -> bf16 (row-major) ----------------
__global__ __launch_bounds__(256) void cvt_bf16(const float* __restrict__ in,
                                                unsigned short* __restrict__ out, int n8)
{
    int i = blockIdx.x * 256 + threadIdx.x;
    if (i >= n8) return;
    float4 v0 = *(const float4*)(in + (size_t)i * 8);
    float4 v1 = *(const float4*)(in + (size_t)i * 8 + 4);
    ushort8 r;
    r[0]=f2b(v0.x); r[1]=f2b(v0.y); r[2]=f2b(v0.z); r[3]=f2b(v0.w);
    r[4]=f2b(v1.x); r[5]=f2b(v1.y); r[6]=f2b(v1.z); r[7]=f2b(v1.w);
    *(ushort8*)(out + (size_t)i * 8) = r;
}

// ---------------- weight prep: WT_t = combined W^T in fragment-tiled layout ------------
// per (l,dst) block of 49152 elems: [ct16][k32][lane=(fk8<<4)|frc][8]
__global__ __launch_bounds__(256) void build_wcomb(
    const float* __restrict__ Wl, const float* __restrict__ bl,
    const float* __restrict__ Wr, unsigned short* __restrict__ WTt, float* __restrict__ bc)
{
    int idx = blockIdx.x * 256 + threadIdx.x;
    if (idx < 2 * 2 * DD * KTOT) {
        int k  = idx % KTOT;
        int t1 = idx / KTOT;
        int i  = t1 & 127;
        int t2 = t1 >> 7;
        int dt = t2 & 1;      // 0 = dst d, 1 = dst m
        int l  = t2 >> 1;
        int ta = dt ? 1 : 0;  // d: dd(0), m: mm(1)
        int tb = dt ? 2 : 3;  // d: md(3), m: dm(2)
        float v;
        if (k < 128) {
            v = Wl[(((size_t)(l * 4 + ta) * 128 + i) << 7) + k];
        } else if (k < 256) {
            v = Wl[(((size_t)(l * 4 + tb) * 128 + i) << 7) + (k - 128)];
        } else {
            int kk = k - 256;
            v = Wr[(((size_t)(l * 4 + ta) * 128 + i) << 7) + kk]
              + Wr[(((size_t)(l * 4 + tb) * 128 + i) << 7) + kk];
        }
        int tidx = ((((i >> 4) * 12 + (k >> 5)) * 64) + (((k >> 3) & 3) * 16 + (i & 15))) * 8
                 + (k & 7);
        WTt[(size_t)t2 * (DD * KTOT) + tidx] = f2b(v);
    }
    if (idx < 512) {
        int i  = idx & 127;
        int t2 = idx >> 7;
        int dt = t2 & 1;
        int l  = t2 >> 1;
        int ta = dt ? 1 : 0;
        int tb = dt ? 2 : 3;
        bc[idx] = bl[(l * 4 + ta) * 128 + i] + bl[(l * 4 + tb) * 128 + i];
    }
}

// ---------------- phase A: LDS-binned edge staging, fixed-CAP bucket regions ----------
__global__ __launch_bounds__(512) void bin_edges(
    const void* __restrict__ e0, const void* __restrict__ e1,
    const void* __restrict__ e2, const void* __restrict__ e3,
    int E0, int E1, int E2, int E3,
    const int* __restrict__ flag, int* __restrict__ bucket_fill,
    unsigned* __restrict__ stage,
    unsigned long long* __restrict__ ovf, int* __restrict__ ovf_cnt,
    int N, int nb)
{
    __shared__ unsigned sb_pack[CHUNK];
    __shared__ unsigned short sb_b[CHUNK];
    __shared__ int hist[NBMAX];
    __shared__ int offs[NBMAX];
    __shared__ int base[NBMAX];

    const int tid   = threadIdx.x;
    const int E_tot = E0 + E1 + E2 + E3;
    const int e_bas = blockIdx.x * CHUNK;
    const int e_end = min(e_bas + CHUNK, E_tot);
    const int cnt_e = e_end - e_bas;
    const int isI32 = *flag;

    for (int i = tid; i < nb; i += 512) hist[i] = 0;
    __syncthreads();

    unsigned my_pack[4];
    int my_b[4], my_r[4];
    #pragma unroll
    for (int u = 0; u < 4; ++u) {
        my_b[u] = -1;
        int e = e_bas + tid + u * 512;
        if (e < e_end) {
            const void* ep; int El, type, le = e;
            if (le < E0)              { ep = e0; El = E0; type = 0; }
            else if ((le -= E0) < E1) { ep = e1; El = E1; type = 1; }
            else if ((le -= E1) < E2) { ep = e2; El = E2; type = 2; }
            else                      { le -= E2; ep = e3; El = E3; type = 3; }
            int s, d;
            if (isI32) {
                s = ((const int*)ep)[le];
                d = ((const int*)ep)[(size_t)El + le];
            } else {
                s = (int)((const long long*)ep)[le];
                d = (int)((const long long*)ep)[(size_t)El + le];
            }
            int gnode = type * N + d;
            int b = gnode >> BS_BITS;
            my_b[u]    = b;
            my_pack[u] = ((unsigned)s << BS_BITS) | (unsigned)(gnode & (BS - 1));
            my_r[u]    = atomicAdd(&hist[b], 1);
        }
    }
    __syncthreads();

    offs[tid] = (tid < nb) ? hist[tid] : 0;
    __syncthreads();
    for (int d = 1; d < 512; d <<= 1) {
        int v = (tid >= d) ? offs[tid - d] : 0;
        __syncthreads();
        offs[tid] += v;
        __syncthreads();
    }
    if (tid < nb) {
        offs[tid] -= hist[tid];                              // exclusive
        base[tid] = hist[tid] ? atomicAdd(&bucket_fill[tid], hist[tid]) : 0;
    }
    __syncthreads();

    #pragma unroll
    for (int u = 0; u < 4; ++u) {
        if (my_b[u] >= 0) {
            int pos = offs[my_b[u]] + my_r[u];
            sb_pack[pos] = my_pack[u];
            sb_b[pos]    = (unsigned short)my_b[u];
        }
    }
    __syncthreads();

    for (int pos = tid; pos < cnt_e; pos += 512) {
        int b = sb_b[pos];
        unsigned p = sb_pack[pos];
        int idx = base[b] + (pos - offs[b]);
        if (idx < CAP) {
            stage[(size_t)b * CAP + idx] = p;
        } else {                                             // overflow (expected: never)
            int k = atomicAdd(ovf_cnt, 1);
            int gnode = (b << BS_BITS) | (int)(p & (BS - 1));
            ovf[k] = ((unsigned long long)(unsigned)gnode << 32) | (p >> BS_BITS);
        }
    }
}

// ---------------- exclusive scan over bucket totals (1 block) ----------------
__global__ __launch_bounds__(512) void scan_buckets(const int* __restrict__ fill, int nb,
                                                    int* __restrict__ base)
{
    __shared__ int s[512];
    const int tid = threadIdx.x;
    int v = (tid < nb) ? fill[tid] : 0;
    s[tid] = v;
    __syncthreads();
    for (int d = 1; d < 512; d <<= 1) {
        int u = (tid >= d) ? s[tid - d] : 0;
        __syncthreads();
        s[tid] += u;
        __syncthreads();
    }
    if (tid < nb) base[tid] = s[tid] - v;    // exclusive
}

// ---------------- phase B: per-bucket count + scan + rp/inv + CSR fill ----------------
__global__ __launch_bounds__(512) void fill_from_stage(
    const unsigned* __restrict__ stage, const int* __restrict__ bucket_fill,
    const int* __restrict__ bucket_base,
    const unsigned long long* __restrict__ ovf, const int* __restrict__ ovf_cnt,
    int* __restrict__ rp_all, float* __restrict__ inv_all, int* __restrict__ col, int n4)
{
    __shared__ int cl[BS];     // counts, later cursors
    __shared__ int rl[BS];     // exclusive scan
    __shared__ int w[512];

    const int tid   = threadIdx.x;
    const int b     = blockIdx.x;
    const int node0 = b << BS_BITS;
    const int nn    = min(BS, n4 - node0);

    cl[tid] = 0; cl[tid + 512] = 0;
    __syncthreads();

    const int total  = bucket_fill[b];
    const int nstage = min(total, CAP);
    const unsigned* st = stage + (size_t)b * CAP;
    const int novf = *ovf_cnt;

    for (int j = tid; j < nstage; j += 512)
        atomicAdd(&cl[st[j] & (BS - 1)], 1);
    for (int k = tid; k < novf; k += 512) {
        int g = (int)(ovf[k] >> 32);
        if (g >= node0 && g < node0 + nn) atomicAdd(&cl[g - node0], 1);
    }
    __syncthreads();

    int a0 = cl[2 * tid], a1 = cl[2 * tid + 1];
    w[tid] = a0 + a1;
    __syncthreads();
    for (int d = 1; d < 512; d <<= 1) {
        int v = (tid >= d) ? w[tid - d] : 0;
        __syncthreads();
        w[tid] += v;
        __syncthreads();
    }
    int excl = w[tid] - a0 - a1;
    rl[2 * tid]     = excl;
    rl[2 * tid + 1] = excl + a0;
    __syncthreads();

    const int gbase = bucket_base[b];
    for (int i = tid; i < nn; i += 512) {
        rp_all[node0 + i] = gbase + rl[i];
        inv_all[node0 + i] = 1.0f / (float)max(cl[i], 1);
    }
    if (b == gridDim.x - 1 && tid == 0) rp_all[n4] = gbase + total;
    __syncthreads();

    for (int i = tid; i < BS; i += 512) cl[i] = gbase + rl[i];
    __syncthreads();

    for (int j = tid; j < nstage; j += 512) {
        unsigned p = st[j];
        int slot = atomicAdd(&cl[p & (BS - 1)], 1);
        col[slot] = (int)(p >> BS_BITS);
    }
    for (int k = tid; k < novf; k += 512) {
        unsigned long long p = ovf[k];
        int g = (int)(p >> 32);
        if (g >= node0 && g < node0 + nn) {
            int slot = atomicAdd(&cl[g - node0], 1);
            col[slot] = (int)(p & 0xffffffffu);
        }
    }
}

// ---------------- gather-aggregate BOTH dst types into fragment-tiled A_t ----------------
// x = [xd rows 0..N-1 | xm rows N..2N-1] row-major bf16. Node n in [0,2N).
// segA = n + (n<N?0:N)  (dd|mm), segB = segA + N (md|dm); rp is one global CSR over 4N.
// A_t per r16 tile (r16 = n>>4): 8 k32-tiles [lane=(fk8<<4)|fr][8]; 0-3 meanSelf, 4-7 meanOther.
__global__ __launch_bounds__(256) void aggregate_all(
    const unsigned short* __restrict__ x, const int* __restrict__ rp,
    const float* __restrict__ inv, const int* __restrict__ col,
    unsigned short* __restrict__ At, int N)
{
    long long g = (long long)blockIdx.x * 256 + threadIdx.x;
    int node = (int)(g >> 4);
    int q    = (int)(g & 15);          // lane handles 8 bf16 = 16 B
    if (node >= 2 * N) return;

    const int isM  = node >= N;
    const int segA = node + (isM ? N : 0);
    const int segB = segA + N;
    const int selfbase  = isM ? N : 0;
    const int otherbase = N - selfbase;

    const int r16 = node >> 4;
    const int fr  = node & 15;
    unsigned short* tbase = At + ((size_t)r16 * 8 + (q >> 2)) * 512 + ((q & 3) * 16 + fr) * 8;

    const unsigned short* xs = x + (size_t)selfbase  * DD + q * 8;
    const unsigned short* xo = x + (size_t)otherbase * DD + q * 8;

    float accA[8], accB[8];
    #pragma unroll
    for (int t = 0; t < 8; ++t) { accA[t] = 0.f; accB[t] = 0.f; }

    int jA = rp[segA], eA = rp[segA + 1];
    int jB = rp[segB], eB = rp[segB + 1];

    // interleaved main loops: 8 independent row-loads in flight
    while (jA + 4 <= eA && jB + 4 <= eB) {
        int a0 = col[jA], a1 = col[jA+1], a2 = col[jA+2], a3 = col[jA+3];
        int b0 = col[jB], b1 = col[jB+1], b2 = col[jB+2], b3 = col[jB+3];
        ushort8 va0 = *(const ushort8*)(xs + (size_t)a0 * DD);
        ushort8 va1 = *(const ushort8*)(xs + (size_t)a1 * DD);
        ushort8 va2 = *(const ushort8*)(xs + (size_t)a2 * DD);
        ushort8 va3 = *(const ushort8*)(xs + (size_t)a3 * DD);
        ushort8 vb0 = *(const ushort8*)(xo + (size_t)b0 * DD);
        ushort8 vb1 = *(const ushort8*)(xo + (size_t)b1 * DD);
        ushort8 vb2 = *(const ushort8*)(xo + (size_t)b2 * DD);
        ushort8 vb3 = *(const ushort8*)(xo + (size_t)b3 * DD);
        #pragma unroll
        for (int t = 0; t < 8; ++t) {
            accA[t] += (b2f(va0[t]) + b2f(va1[t])) + (b2f(va2[t]) + b2f(va3[t]));
            accB[t] += (b2f(vb0[t]) + b2f(vb1[t])) + (b2f(vb2[t]) + b2f(vb3[t]));
        }
        jA += 4; jB += 4;
    }
    while (jA + 4 <= eA) {
        int a0 = col[jA], a1 = col[jA+1], a2 = col[jA+2], a3 = col[jA+3];
        ushort8 va0 = *(const ushort8*)(xs + (size_t)a0 * DD);
        ushort8 va1 = *(const ushort8*)(xs + (size_t)a1 * DD);
        ushort8 va2 = *(const ushort8*)(xs + (size_t)a2 * DD);
        ushort8 va3 = *(const ushort8*)(xs + (size_t)a3 * DD);
        #pragma unroll
        for (int t = 0; t < 8; ++t)
            accA[t] += (b2f(va0[t]) + b2f(va1[t])) + (b2f(va2[t]) + b2f(va3[t]));
        jA += 4;
    }
    while (jB + 4 <= eB) {
        int b0 = col[jB], b1 = col[jB+1], b2 = col[jB+2], b3 = col[jB+3];
        ushort8 vb0 = *(const ushort8*)(xo + (size_t)b0 * DD);
        ushort8 vb1 = *(const ushort8*)(xo + (size_t)b1 * DD);
        ushort8 vb2 = *(const ushort8*)(xo + (size_t)b2 * DD);
        ushort8 vb3 = *(const ushort8*)(xo + (size_t)b3 * DD);
        #pragma unroll
        for (int t = 0; t < 8; ++t)
            accB[t] += (b2f(vb0[t]) + b2f(vb1[t])) + (b2f(vb2[t]) + b2f(vb3[t]));
        jB += 4;
    }
    for (; jA < eA; ++jA) {
        ushort8 v = *(const ushort8*)(xs + (size_t)col[jA] * DD);
        #pragma unroll
        for (int t = 0; t < 8; ++t) accA[t] += b2f(v[t]);
    }
    for (; jB < eB; ++jB) {
        ushort8 v = *(const ushort8*)(xo + (size_t)col[jB] * DD);
        #pragma unroll
        for (int t = 0; t < 8; ++t) accB[t] += b2f(v[t]);
    }

    float scA = inv[segA], scB = inv[segB];
    ushort8 rA, rB;
    #pragma unroll
    for (int t = 0; t < 8; ++t) { rA[t] = f2b(accA[t] * scA); rB[t] = f2b(accB[t] * scB); }
    *(ushort8*)(tbase)           = rA;
    *(ushort8*)(tbase + 4 * 512) = rB;
}

// ---------------- MFMA GEMM, LDS-free, both dst types in one grid ----------------
// blocks [0,gd) = dst d (rows 0..N-1), [gd,gd+gm) = dst m (rows N..2N-1).
// A: k32 0..7 from tiled At; k32 8..11 directly from row-major x (self rows).
__global__ __launch_bounds__(256) void gemm_mfma(
    const unsigned short* __restrict__ At, const unsigned short* __restrict__ x,
    const unsigned short* __restrict__ WTt, const float* __restrict__ bc,
    void* __restrict__ outp, int relu, int write_f32, int N, int gd)
{
    const int tid = threadIdx.x;
    const int b   = blockIdx.x;
    const int isM = (b >= gd);
    const int row0   = isM ? N + (b - gd) * BM : b * BM;
    const int rowlim = isM ? 2 * N : N;
    const int tlim   = (rowlim >> 4) - 1;

    const unsigned short* WT   = WTt + (size_t)isM * DD * KTOT;
    const float*          bias = bc + isM * DD;

    const int wave = tid >> 6;
    const int lane = tid & 63;
    const int wr = (wave >> 1) * 32;         // 0 / 32
    const int wc = (wave & 1) * 64;          // 0 / 64
    const int fr  = lane & 15;
    const int fk8 = lane >> 4;

    int r16a = (row0 >> 4) + (wave >> 1) * 2;
    int r16b = r16a + 1;
    if (r16a > tlim) r16a = tlim;
    if (r16b > tlim) r16b = tlim;

    const unsigned short* Abase0 = At + (size_t)r16a * 8 * 512 + lane * 8;
    const unsigned short* Abase1 = At + (size_t)r16b * 8 * 512 + lane * 8;
    const unsigned short* Xbase0 = x + (size_t)(r16a * 16 + fr) * DD + fk8 * 8;
    const unsigned short* Xbase1 = x + (size_t)(r16b * 16 + fr) * DD + fk8 * 8;
    const unsigned short* Wbase  = WTt + (size_t)isM * DD * KTOT + (size_t)(wc >> 4) * 12 * 512 + lane * 8;

    floatx4 acc[2][4] = {};

    short8 a0c, a1c, a0n, a1n, bC[4], bN[4];
    a0c = *(const short8*)(Abase0);
    a1c = *(const short8*)(Abase1);
    #pragma unroll
    for (int c = 0; c < 4; ++c) bC[c] = *(const short8*)(Wbase + (size_t)c * 12 * 512);

    #pragma unroll
    for (int ks = 0; ks < 12; ++ks) {
        if (ks < 11) {
            int kn = ks + 1;
            if (kn < 8) {
                a0n = *(const short8*)(Abase0 + kn * 512);
                a1n = *(const short8*)(Abase1 + kn * 512);
            } else {
                a0n = *(const short8*)(Xbase0 + (kn - 8) * 32);
                a1n = *(const short8*)(Xbase1 + (kn - 8) * 32);
            }
            #pragma unroll
            for (int c = 0; c < 4; ++c) bN[c] = *(const short8*)(Wbase + (size_t)c * 12 * 512 + kn * 512);
        }
        #pragma unroll
        for (int c = 0; c < 4; ++c) {
            acc[0][c] = __builtin_amdgcn_mfma_f32_16x16x32_bf16(a0c, bC[c], acc[0][c], 0, 0, 0);
            acc[1][c] = __builtin_amdgcn_mfma_f32_16x16x32_bf16(a1c, bC[c], acc[1][c], 0, 0, 0);
        }
        a0c = a0n; a1c = a1n;
        #pragma unroll
        for (int c = 0; c < 4; ++c) bC[c] = bN[c];
    }

    // epilogue: col = wc + c*16 + (lane&15), row = wr + m*16 + (lane>>4)*4 + i  [m89 layout]
    float* outf = (float*)outp;
    unsigned short* outb = (unsigned short*)outp;
    const int rb = (lane >> 4) * 4;
    #pragma unroll
    for (int c = 0; c < 4; ++c) {
        int ocol = wc + c * 16 + fr;
        float bb = bias[ocol];
        #pragma unroll
        for (int m = 0; m < 2; ++m) {
            #pragma unroll
            for (int i = 0; i < 4; ++i) {
                int orow = row0 + wr + m * 16 + rb + i;
                if (orow >= rowlim) continue;
                float v = acc[m][c][i] + bb;
                if (relu) v = fmaxf(v, 0.f);
                if (write_f32) outf[(size_t)orow * DD + ocol] = v;
                else           outb[(size_t)orow * DD + ocol] = f2b(v);
            }
        }
    }
}

extern "C" void kernel_launch(void* const* d_in, const int* in_sizes, int n_in,
                              void* d_out, int out_size, void* d_ws, size_t ws_size,
                              hipStream_t stream)
{
    const float* x_d = (const float*)d_in[0];
    const float* x_m = (const float*)d_in[1];
    const float* Wl  = (const float*)d_in[6];
    const float* bl  = (const float*)d_in[7];
    const float* Wr  = (const float*)d_in[8];
    float* out = (float*)d_out;

    const int N    = in_sizes[0] / DD;
    const int E_dd = in_sizes[2] / 2;
    const int E_mm = in_sizes[3] / 2;
    const int E_dm = in_sizes[4] / 2;
    const int E_md = in_sizes[5] / 2;
    const int E_tot = E_dd + E_md + E_mm + E_dm;
    const int n4 = 4 * N;
    const int nb = (n4 + BS - 1) >> BS_BITS;
    const int M16 = (2 * N + 15) >> 4;

    char* ws = (char*)d_ws;
    size_t off = 0;
    auto alloc = [&](size_t bytes) {
        void* p = ws + off;
        off += (bytes + 255) & ~(size_t)255;
        return p;
    };
    unsigned short* xb    = (unsigned short*)alloc((size_t)2 * N * DD * 2);  // [xd|xm]
    unsigned short* hb    = (unsigned short*)alloc((size_t)2 * N * DD * 2);  // [hd|hm]
    unsigned short* At    = (unsigned short*)alloc((size_t)M16 * 8 * 512 * 2);
    float* inv_all = (float*)alloc((size_t)n4 * 4);
    int*   rp_all  = (int*)  alloc((size_t)(n4 + 1) * 4);
    int*   bucket_fill = (int*)alloc((size_t)NBMAX * 4);
    int*   bucket_base = (int*)alloc((size_t)NBMAX * 4);
    unsigned short* WTt = (unsigned short*)alloc((size_t)2 * 2 * DD * KTOT * 2);
    float* bc      = (float*)alloc((size_t)512 * 4);
    unsigned* stage = (unsigned*)alloc((size_t)nb * CAP * 4);
    int*   col     = (int*)alloc((size_t)E_tot * 4);
    unsigned long long* ovf = (unsigned long long*)alloc((size_t)(1 << 18) * 8);
    int*   ovf_cnt = (int*)alloc(256);
    int*   flag    = (int*)alloc(256);

    // ---- edge dtype probe ----
    hipMemsetAsync(flag, 0, 256, stream);
    detect_i32<<<4, 256, 0, stream>>>((const int*)d_in[2], 1024, flag);

    // ---- x -> bf16 ([xd|xm] contiguous) ----
    const int n8 = N * DD / 8;
    cvt_bf16<<<(n8 + 255) / 256, 256, 0, stream>>>(x_d, xb, n8);
    cvt_bf16<<<(n8 + 255) / 256, 256, 0, stream>>>(x_m, xb + (size_t)N * DD, n8);

    // ---- CSR build: bin -> bucket scan -> per-bucket count/scan/fill ----
    hipMemsetAsync(bucket_fill, 0, (size_t)NBMAX * 4, stream);
    hipMemsetAsync(ovf_cnt, 0, 256, stream);
    const int nchunks = (E_tot + CHUNK - 1) / CHUNK;
    bin_edges<<<nchunks, 512, 0, stream>>>(
        d_in[2], d_in[5], d_in[3], d_in[4], E_dd, E_md, E_mm, E_dm,
        flag, bucket_fill, stage, ovf, ovf_cnt, N, nb);
    scan_buckets<<<1, 512, 0, stream>>>(bucket_fill, nb, bucket_base);
    fill_from_stage<<<nb, 512, 0, stream>>>(
        stage, bucket_fill, bucket_base, ovf, ovf_cnt, rp_all, inv_all, col, n4);

    build_wcomb<<<(2 * 2 * DD * KTOT + 255) / 256, 256, 0, stream>>>(Wl, bl, Wr, WTt, bc);

    const int agg_grid = (int)(((size_t)2 * N * 16 + 255) / 256);
    const int gd = (N + BM - 1) / BM;
    const int gemm_grid = 2 * gd;
    const unsigned short* xcur = xb;
    for (int l = 0; l < 2; ++l) {
        int relu = (l == 0);
        int wf32 = (l == 1);
        void* ob = (l == 1) ? (void*)out : (void*)hb;

        aggregate_all<<<agg_grid, 256, 0, stream>>>(xcur, rp_all, inv_all, col, At, N);
        gemm_mfma<<<gemm_grid, 256, 0, stream>>>(
            At, xcur, WTt + (size_t)l * 2 * DD * KTOT, bc + l * 2 * DD,
            ob, relu, wf32, N, gd);

        xcur = hb;
    }
}